// Round 4
// baseline (917.717 us; speedup 1.0000x reference)
//
#include <hip/hip_runtime.h>
#include <hip/hip_bf16.h>

#define N_NODES 50000
#define N_EDGES 1600000
#define N_GRAPHS 64

#define RANGES 8
#define BPR    16                  // edge slices per range
#define BINS   6256                // RANGES*BINS = 50048 >= N_NODES
#define NBINS_TOT (RANGES * BINS)  // 50048
#define EPS    (N_EDGES / BPR)     // 100000 (exact)

// ---------- helpers ----------
__device__ __forceinline__ unsigned fenc(float x) {
    unsigned u = __float_as_uint(x);
    return (u & 0x80000000u) ? ~u : (u | 0x80000000u);
}
__device__ __forceinline__ float fdec(unsigned e) {
    return (e & 0x80000000u) ? __uint_as_float(e & 0x7fffffffu) : __uint_as_float(~e);
}

// ---------- LDS-privatized histogram: cnt + deg per node, no global atomics ----------
__global__ void hist_lds(const int* __restrict__ dst, const float* __restrict__ ew,
                         int* __restrict__ sc, float* __restrict__ sd) {
    __shared__ int   hc[BINS];
    __shared__ float hd[BINS];
    for (int i = threadIdx.x; i < BINS; i += 256) { hc[i] = 0; hd[i] = 0.f; }
    __syncthreads();
    const int r  = blockIdx.x & (RANGES - 1);
    const int s  = blockIdx.x >> 3;             // / RANGES
    const int lo = r * BINS, hi = lo + BINS;
    const int e0 = s * EPS;
    for (int e = e0 + threadIdx.x; e < e0 + EPS; e += 256) {
        int d = dst[e];
        if (d >= lo && d < hi) {
            atomicAdd(&hc[d - lo], 1);
            atomicAdd(&hd[d - lo], ew[e]);
        }
    }
    __syncthreads();
    int base = (r * BPR + s) * BINS;
    for (int i = threadIdx.x; i < BINS; i += 256) {
        sc[base + i] = hc[i];
        sd[base + i] = hd[i];
    }
}

// ---------- sum slices -> cnt, deg->dinv, block partial sums ----------
__global__ void sum_dinv_bsum(const int* __restrict__ sc, const float* __restrict__ sd,
                              int* __restrict__ cnt, float* __restrict__ dinv,
                              int* __restrict__ bsum) {
    __shared__ int sh[256];
    int idx = blockIdx.x * 256 + threadIdx.x;
    int c = 0;
    if (idx < NBINS_TOT) {
        int r = idx / BINS, j = idx - r * BINS;
        int base = (r * BPR) * BINS + j;
        float dg = 0.f;
        #pragma unroll
        for (int s = 0; s < BPR; ++s) { c += sc[base + s * BINS]; dg += sd[base + s * BINS]; }
        cnt[idx] = c;
        if (idx < N_NODES) dinv[idx] = rsqrtf(dg + 1.0f);
    }
    sh[threadIdx.x] = c;
    __syncthreads();
    for (int o = 128; o; o >>= 1) {
        if (threadIdx.x < o) sh[threadIdx.x] += sh[threadIdx.x + o];
        __syncthreads();
    }
    if (threadIdx.x == 0) bsum[blockIdx.x] = sh[0];
}

__global__ void scan_bsums(const int* __restrict__ bsum, int* __restrict__ boff, int nb) {
    __shared__ int s[256];
    int v = (threadIdx.x < nb) ? bsum[threadIdx.x] : 0;
    s[threadIdx.x] = v;
    __syncthreads();
    for (int o = 1; o < 256; o <<= 1) {
        int t = 0;
        if (threadIdx.x >= o) t = s[threadIdx.x - o];
        __syncthreads();
        s[threadIdx.x] += t;
        __syncthreads();
    }
    if (threadIdx.x < nb) boff[threadIdx.x] = s[threadIdx.x] - v;   // exclusive
}

// ---------- scan over bins -> row_start; per-(range,slice) bin offsets -> soff ----------
__global__ void scan_counts_off(const int* __restrict__ cnt, const int* __restrict__ boff,
                                const int* __restrict__ sc,
                                int* __restrict__ row_start, int* __restrict__ soff) {
    __shared__ int sh[256];
    int idx = blockIdx.x * 256 + threadIdx.x;
    int v = (idx < NBINS_TOT) ? cnt[idx] : 0;
    sh[threadIdx.x] = v;
    __syncthreads();
    for (int o = 1; o < 256; o <<= 1) {
        int t = 0;
        if (threadIdx.x >= o) t = sh[threadIdx.x - o];
        __syncthreads();
        sh[threadIdx.x] += t;
        __syncthreads();
    }
    if (idx < NBINS_TOT) {
        int ex = boff[blockIdx.x] + sh[threadIdx.x] - v;   // exclusive scan
        row_start[idx] = ex;
        int r = idx / BINS, j = idx - r * BINS;
        int base = (r * BPR) * BINS + j;
        int run = ex;
        #pragma unroll
        for (int s = 0; s < BPR; ++s) { soff[base + s * BINS] = run; run += sc[base + s * BINS]; }
    }
}

// ---------- fill CSR via LDS cursors: packed {src, coef}, no global atomics ----------
__global__ void fill_lds(const int* __restrict__ src, const int* __restrict__ dst,
                         const float* __restrict__ ew, const float* __restrict__ dinv,
                         const int* __restrict__ soff, uint2* __restrict__ csr) {
    __shared__ int cur[BINS];
    const int r = blockIdx.x & (RANGES - 1);
    const int s = blockIdx.x >> 3;
    int base = (r * BPR + s) * BINS;
    for (int i = threadIdx.x; i < BINS; i += 256) cur[i] = soff[base + i];
    __syncthreads();
    const int lo = r * BINS, hi = lo + BINS;
    const int e0 = s * EPS;
    for (int e = e0 + threadIdx.x; e < e0 + EPS; e += 256) {
        int d = dst[e];
        if (d >= lo && d < hi) {
            int sv = src[e];
            float c = dinv[sv] * ew[e] * dinv[d];
            int pos = atomicAdd(&cur[d - lo], 1);
            csr[pos] = make_uint2((unsigned)sv, __float_as_uint(c));
        }
    }
}

// ---------- GEMM1: Y(chunk-major [8][N][16]) = X[N,128] @ W[128,128], 4x4 reg tile ----------
__global__ void gemm1_reg(const float* __restrict__ X, const float* __restrict__ W,
                          float* __restrict__ Y, int nrows) {
    __shared__ float Xl[32][132];
    __shared__ float Wl[64][128];
    const int rt = threadIdx.x >> 5;   // 0..7  (4 rows each)
    const int ct = threadIdx.x & 31;   // 0..31 (4 cols each)
    const int base = blockIdx.x * 32;
    for (int i = threadIdx.x; i < 32 * 32; i += 256) {
        int rr = i >> 5, cc = (i & 31) << 2;
        int gr = base + rr;
        float4 v = (gr < nrows) ? *(const float4*)&X[(size_t)gr * 128 + cc]
                                : make_float4(0.f, 0.f, 0.f, 0.f);
        Xl[rr][cc] = v.x; Xl[rr][cc + 1] = v.y; Xl[rr][cc + 2] = v.z; Xl[rr][cc + 3] = v.w;
    }
    float acc[4][4] = {};
    for (int kb = 0; kb < 128; kb += 64) {
        __syncthreads();
        for (int i = threadIdx.x; i < 64 * 32; i += 256) {
            int kk = i >> 5, cc = (i & 31) << 2;
            *(float4*)&Wl[kk][cc] = *(const float4*)&W[(size_t)(kb + kk) * 128 + cc];
        }
        __syncthreads();
        for (int k = 0; k < 64; k += 4) {
            float4 a0 = *(const float4*)&Xl[rt * 4 + 0][kb + k];
            float4 a1 = *(const float4*)&Xl[rt * 4 + 1][kb + k];
            float4 a2 = *(const float4*)&Xl[rt * 4 + 2][kb + k];
            float4 a3 = *(const float4*)&Xl[rt * 4 + 3][kb + k];
            float4 w0 = *(const float4*)&Wl[k + 0][ct * 4];
            float4 w1 = *(const float4*)&Wl[k + 1][ct * 4];
            float4 w2 = *(const float4*)&Wl[k + 2][ct * 4];
            float4 w3 = *(const float4*)&Wl[k + 3][ct * 4];
            #define STEP(av, wv)  \
                acc[0][0] += av##0 * wv.x; acc[0][1] += av##0 * wv.y; acc[0][2] += av##0 * wv.z; acc[0][3] += av##0 * wv.w; \
                acc[1][0] += av##1 * wv.x; acc[1][1] += av##1 * wv.y; acc[1][2] += av##1 * wv.z; acc[1][3] += av##1 * wv.w; \
                acc[2][0] += av##2 * wv.x; acc[2][1] += av##2 * wv.y; acc[2][2] += av##2 * wv.z; acc[2][3] += av##2 * wv.w; \
                acc[3][0] += av##3 * wv.x; acc[3][1] += av##3 * wv.y; acc[3][2] += av##3 * wv.z; acc[3][3] += av##3 * wv.w;
            { float ax0=a0.x, ax1=a1.x, ax2=a2.x, ax3=a3.x; STEP(ax, w0) }
            { float ay0=a0.y, ay1=a1.y, ay2=a2.y, ay3=a3.y; STEP(ay, w1) }
            { float az0=a0.z, az1=a1.z, az2=a2.z, az3=a3.z; STEP(az, w2) }
            { float aw0=a0.w, aw1=a1.w, aw2=a2.w, aw3=a3.w; STEP(aw, w3) }
            #undef STEP
        }
    }
    const int chunk = ct >> 2;
    const int ccol  = (ct & 3) * 4;
    for (int i = 0; i < 4; ++i) {
        int gr = base + rt * 4 + i;
        if (gr < nrows) {
            float4 v = make_float4(acc[i][0], acc[i][1], acc[i][2], acc[i][3]);
            *(float4*)&Y[((size_t)chunk * nrows + gr) * 16 + ccol] = v;
        }
    }
}

// ---------- GEMM2: Y(chunk-major [4][N][16]) = X[N,128] @ W[128,64], 4x2 reg tile ----------
__global__ void gemm2_reg(const float* __restrict__ X, const float* __restrict__ W,
                          float* __restrict__ Y, int nrows) {
    __shared__ float Xl[32][132];
    __shared__ float Wl[128][64];
    const int rt = threadIdx.x >> 5;   // 0..7  (4 rows)
    const int ct = threadIdx.x & 31;   // 0..31 (2 cols)
    const int base = blockIdx.x * 32;
    for (int i = threadIdx.x; i < 32 * 32; i += 256) {
        int rr = i >> 5, cc = (i & 31) << 2;
        int gr = base + rr;
        float4 v = (gr < nrows) ? *(const float4*)&X[(size_t)gr * 128 + cc]
                                : make_float4(0.f, 0.f, 0.f, 0.f);
        Xl[rr][cc] = v.x; Xl[rr][cc + 1] = v.y; Xl[rr][cc + 2] = v.z; Xl[rr][cc + 3] = v.w;
    }
    for (int i = threadIdx.x; i < 128 * 16; i += 256) {
        int kk = i >> 4, cc = (i & 15) << 2;
        *(float4*)&Wl[kk][cc] = *(const float4*)&W[(size_t)kk * 64 + cc];
    }
    float acc[4][2] = {};
    __syncthreads();
    for (int k = 0; k < 128; k += 4) {
        float4 a0 = *(const float4*)&Xl[rt * 4 + 0][k];
        float4 a1 = *(const float4*)&Xl[rt * 4 + 1][k];
        float4 a2 = *(const float4*)&Xl[rt * 4 + 2][k];
        float4 a3 = *(const float4*)&Xl[rt * 4 + 3][k];
        float2 w0 = *(const float2*)&Wl[k + 0][ct * 2];
        float2 w1 = *(const float2*)&Wl[k + 1][ct * 2];
        float2 w2 = *(const float2*)&Wl[k + 2][ct * 2];
        float2 w3 = *(const float2*)&Wl[k + 3][ct * 2];
        acc[0][0] += a0.x * w0.x; acc[0][1] += a0.x * w0.y;
        acc[1][0] += a1.x * w0.x; acc[1][1] += a1.x * w0.y;
        acc[2][0] += a2.x * w0.x; acc[2][1] += a2.x * w0.y;
        acc[3][0] += a3.x * w0.x; acc[3][1] += a3.x * w0.y;
        acc[0][0] += a0.y * w1.x; acc[0][1] += a0.y * w1.y;
        acc[1][0] += a1.y * w1.x; acc[1][1] += a1.y * w1.y;
        acc[2][0] += a2.y * w1.x; acc[2][1] += a2.y * w1.y;
        acc[3][0] += a3.y * w1.x; acc[3][1] += a3.y * w1.y;
        acc[0][0] += a0.z * w2.x; acc[0][1] += a0.z * w2.y;
        acc[1][0] += a1.z * w2.x; acc[1][1] += a1.z * w2.y;
        acc[2][0] += a2.z * w2.x; acc[2][1] += a2.z * w2.y;
        acc[3][0] += a3.z * w2.x; acc[3][1] += a3.z * w2.y;
        acc[0][0] += a0.w * w3.x; acc[0][1] += a0.w * w3.y;
        acc[1][0] += a1.w * w3.x; acc[1][1] += a1.w * w3.y;
        acc[2][0] += a2.w * w3.x; acc[2][1] += a2.w * w3.y;
        acc[3][0] += a3.w * w3.x; acc[3][1] += a3.w * w3.y;
    }
    const int col0  = ct * 2;
    const int chunk = col0 >> 4;
    const int ccol  = col0 & 15;
    for (int i = 0; i < 4; ++i) {
        int gr = base + rt * 4 + i;
        if (gr < nrows) {
            float2 v = make_float2(acc[i][0], acc[i][1]);
            *(float2*)&Y[((size_t)chunk * nrows + gr) * 16 + ccol] = v;
        }
    }
}

// ---------- CSR aggregation from chunk-major xw (packed csr), fused epilogue ----------
template<int NC>
__global__ void agg_csr_chunk(const int* __restrict__ row_start, const uint2* __restrict__ csr,
                              const float* __restrict__ xwc, const float* __restrict__ dinv,
                              const float* __restrict__ b, float* __restrict__ out_h) {
    constexpr int OUT = NC * 16;
    const int c  = blockIdx.x % NC;
    const int nb = blockIdx.x / NC;
    const int n  = nb * 16 + (threadIdx.x >> 4);
    const int kk = threadIdx.x & 15;
    if (n >= N_NODES) return;
    const float* __restrict__ base = xwc + (size_t)c * N_NODES * 16 + kk;
    const int beg = row_start[n], end = row_start[n + 1];
    float acc = 0.f;
    int i = beg;
    for (; i + 3 < end; i += 4) {
        uint2 e0 = csr[i], e1 = csr[i + 1], e2 = csr[i + 2], e3 = csr[i + 3];
        acc += __uint_as_float(e0.y) * base[(size_t)e0.x * 16]
             + __uint_as_float(e1.y) * base[(size_t)e1.x * 16]
             + __uint_as_float(e2.y) * base[(size_t)e2.x * 16]
             + __uint_as_float(e3.y) * base[(size_t)e3.x * 16];
    }
    for (; i < end; ++i) acc += __uint_as_float(csr[i].y) * base[(size_t)csr[i].x * 16];
    float di = dinv[n];
    int kg = c * 16 + kk;
    float v = acc + di * di * base[(size_t)n * 16] + b[kg];
    out_h[(size_t)n * OUT + kg] = fmaxf(v, 0.f);
}

// ---------- gate ----------
__global__ void gate_kernel(const float* __restrict__ x1, const float* __restrict__ gW1,
                            const float* __restrict__ gb1, const float* __restrict__ gW2,
                            const float* __restrict__ gb2, const int* __restrict__ batch,
                            float* __restrict__ g, unsigned* __restrict__ gmax_enc) {
    __shared__ float W1l[64 * 32];
    __shared__ float W2l[32];
    __shared__ float b1l[32];
    for (int i = threadIdx.x; i < 64 * 32; i += 256) W1l[i] = gW1[i];
    if (threadIdx.x < 32) { W2l[threadIdx.x] = gW2[threadIdx.x]; b1l[threadIdx.x] = gb1[threadIdx.x]; }
    __syncthreads();
    const float gb2v = gb2[0];
    int n = blockIdx.x * 256 + threadIdx.x;
    bool act = (n < N_NODES);
    float gv = -1e30f;
    int b = 0;
    if (act) {
        const float* row = x1 + (size_t)n * 64;
        float t[32];
        #pragma unroll
        for (int j = 0; j < 32; ++j) t[j] = b1l[j];
        for (int k = 0; k < 64; ++k) {
            float xv = row[k];
            #pragma unroll
            for (int j = 0; j < 32; ++j) t[j] += xv * W1l[k * 32 + j];
        }
        float a = gb2v;
        #pragma unroll
        for (int j = 0; j < 32; ++j) a += fmaxf(t[j], 0.f) * W2l[j];
        gv = a;
        g[n] = a;
        b = batch[n];
    }
    unsigned long long actm = __ballot(act);
    int b0 = __shfl(b, 0);
    bool uniform = (actm == ~0ull) && (__ballot(b == b0) == ~0ull);
    if (uniform) {
        float m = gv;
        for (int o = 32; o; o >>= 1) m = fmaxf(m, __shfl_xor(m, o));
        if ((threadIdx.x & 63) == 0) atomicMax(&gmax_enc[b0], fenc(m));
    } else if (act) {
        atomicMax(&gmax_enc[b], fenc(gv));
    }
}

__global__ void exp_kernel(const float* __restrict__ g, const int* __restrict__ batch,
                           const unsigned* __restrict__ gmax_enc, float* __restrict__ ex,
                           float* __restrict__ den) {
    int n = blockIdx.x * 256 + threadIdx.x;
    bool act = (n < N_NODES);
    float v = 0.f; int b = 0;
    if (act) {
        b = batch[n];
        v = expf(g[n] - fdec(gmax_enc[b]));
        ex[n] = v;
    }
    unsigned long long actm = __ballot(act);
    int b0 = __shfl(b, 0);
    bool uniform = (actm == ~0ull) && (__ballot(b == b0) == ~0ull);
    if (uniform) {
        float s = v;
        for (int o = 32; o; o >>= 1) s += __shfl_xor(s, o);
        if ((threadIdx.x & 63) == 0) atomicAdd(&den[b0], s);
    } else if (act) {
        atomicAdd(&den[b], v);
    }
}

__global__ void alpha_kernel(float* __restrict__ ex, const int* __restrict__ batch,
                             const float* __restrict__ den) {
    int n = blockIdx.x * 256 + threadIdx.x;
    if (n < N_NODES) ex[n] = ex[n] / den[batch[n]];
}

__global__ void pool_kernel(const float* __restrict__ x1, const float* __restrict__ alpha,
                            const int* __restrict__ batch, float* __restrict__ pooled) {
    const int L = 32;
    const int f   = threadIdx.x & 63;
    const int grp = threadIdx.x >> 6;
    int chunk = blockIdx.x * 4 + grp;
    int start = chunk * L;
    if (start >= N_NODES) return;
    int end = min(start + L, N_NODES);
    int cur = batch[start];
    float acc = 0.f;
    for (int n = start; n < end; ++n) {
        int bb = batch[n];
        if (bb != cur) { atomicAdd(&pooled[cur * 64 + f], acc); acc = 0.f; cur = bb; }
        acc += alpha[n] * x1[(size_t)n * 64 + f];
    }
    atomicAdd(&pooled[cur * 64 + f], acc);
}

__global__ void head_kernel(const float* __restrict__ pooled, const float* __restrict__ fcW1,
                            const float* __restrict__ fcb1, const float* __restrict__ fcW2,
                            const float* __restrict__ fcb2, float* __restrict__ out) {
    __shared__ float P[64 * 64];
    __shared__ float W1l[64 * 128];
    __shared__ float H[64 * 128];
    for (int i = threadIdx.x; i < 64 * 64; i += 256) P[i] = pooled[i];
    for (int i = threadIdx.x; i < 64 * 128; i += 256) W1l[i] = fcW1[i];
    __syncthreads();
    for (int i = threadIdx.x; i < 64 * 128; i += 256) {
        int gi = i >> 7, j = i & 127;
        float a = fcb1[j];
        for (int k = 0; k < 64; ++k) a += P[gi * 64 + k] * W1l[k * 128 + j];
        H[i] = fmaxf(a, 0.f);
    }
    __syncthreads();
    if (threadIdx.x < 64) {
        int gi = threadIdx.x;
        float l0 = fcb2[0], l1 = fcb2[1];
        for (int k = 0; k < 128; ++k) {
            float h = H[gi * 128 + k];
            l0 += h * fcW2[k * 2 + 0];
            l1 += h * fcW2[k * 2 + 1];
        }
        float m = fmaxf(l0, l1);
        float lse = m + logf(expf(l0 - m) + expf(l1 - m));
        out[gi * 2 + 0] = l0 - lse;
        out[gi * 2 + 1] = l1 - lse;
    }
}

extern "C" void kernel_launch(void* const* d_in, const int* in_sizes, int n_in,
                              void* d_out, int out_size, void* d_ws, size_t ws_size,
                              hipStream_t stream) {
    const float* x    = (const float*)d_in[0];
    const int*   ei   = (const int*)d_in[1];
    const float* ew   = (const float*)d_in[2];
    const int*   batch= (const int*)d_in[3];
    const float* W1   = (const float*)d_in[4];
    const float* b1   = (const float*)d_in[5];
    const float* W2   = (const float*)d_in[6];
    const float* b2   = (const float*)d_in[7];
    const float* gW1  = (const float*)d_in[8];
    const float* gb1  = (const float*)d_in[9];
    const float* gW2  = (const float*)d_in[10];
    const float* gb2  = (const float*)d_in[11];
    const float* fcW1 = (const float*)d_in[12];
    const float* fcb1 = (const float*)d_in[13];
    const float* fcW2 = (const float*)d_in[14];
    const float* fcb2 = (const float*)d_in[15];
    float* out = (float*)d_out;

    const int* src = ei;
    const int* dst = ei + N_EDGES;

    const int NB = (N_NODES + 255) / 256;          // 196
    const int SB = (NBINS_TOT + 255) / 256;        // 196 (scan grid over 50048 bins)
    const int NBLK16 = (N_NODES + 15) / 16;        // 3125
    const int HIST_GRID = RANGES * BPR;            // 128

    // ---- workspace layout (floats) ----
    float* ws = (float*)d_ws;
    float* xw    = ws;                             // 6,400,000 (chunk-major [NC][N][16])
    float* agg   = ws + 6400000;                   // 6,400,000 (row-major h / x1)
    size_t off = 12800000;
    uint2* csr      = (uint2*)(ws + off);  off += 3200000;   // packed {src, coef}
    int*   row_start= (int*)(ws + off);    off += 50176;
    int*   cnt      = (int*)(ws + off);    off += 50176;
    float* dinv     = ws + off;            off += 50176;
    float* g        = ws + off;            off += 50048;
    float* ex       = ws + off;            off += 50048;
    int*   bsum     = (int*)(ws + off);    off += 256;
    int*   boff     = (int*)(ws + off);    off += 256;
    unsigned* gmax  = (unsigned*)(ws + off); off += 64;
    float* den      = ws + off;            off += 64;
    float* pooled   = ws + off;            off += 4096;
    // histogram scratch overlays xw (dead until gemm1): 3 x 800,768 words = 9.6 MB < 25.6 MB
    int*   sc   = (int*)xw;                        // [RANGES][BPR][BINS]
    float* sd   = (float*)(xw + 800768);
    int*   soff = (int*)(xw + 1601536);

    // ---- CSR build (no global atomics) ----
    hist_lds<<<HIST_GRID, 256, 0, stream>>>(dst, ew, sc, sd);
    sum_dinv_bsum<<<SB, 256, 0, stream>>>(sc, sd, cnt, dinv, bsum);
    scan_bsums<<<1, 256, 0, stream>>>(bsum, boff, SB);
    scan_counts_off<<<SB, 256, 0, stream>>>(cnt, boff, sc, row_start, soff);
    fill_lds<<<HIST_GRID, 256, 0, stream>>>(src, dst, ew, dinv, soff, csr);

    // ---- conv1 ----
    gemm1_reg<<<(N_NODES + 31) / 32, 256, 0, stream>>>(x, W1, xw, N_NODES);
    agg_csr_chunk<8><<<8 * NBLK16, 256, 0, stream>>>(row_start, csr, xw, dinv, b1, agg);

    // ---- conv2 ----
    gemm2_reg<<<(N_NODES + 31) / 32, 256, 0, stream>>>(agg, W2, xw, N_NODES);
    agg_csr_chunk<4><<<4 * NBLK16, 256, 0, stream>>>(row_start, csr, xw, dinv, b2, agg);

    // ---- global attention ----
    hipMemsetAsync(gmax, 0, N_GRAPHS * sizeof(unsigned), stream);
    hipMemsetAsync(den, 0, N_GRAPHS * sizeof(float), stream);
    hipMemsetAsync(pooled, 0, N_GRAPHS * 64 * sizeof(float), stream);
    gate_kernel<<<NB, 256, 0, stream>>>(agg, gW1, gb1, gW2, gb2, batch, g, gmax);
    exp_kernel<<<NB, 256, 0, stream>>>(g, batch, gmax, ex, den);
    alpha_kernel<<<NB, 256, 0, stream>>>(ex, batch, den);
    int nchunks = (N_NODES + 31) / 32;
    pool_kernel<<<(nchunks + 3) / 4, 256, 0, stream>>>(agg, ex, batch, pooled);

    // ---- head ----
    head_kernel<<<1, 256, 0, stream>>>(pooled, fcW1, fcb1, fcW2, fcb2, out);
}

// Round 5
// 639.126 us; speedup vs baseline: 1.4359x; 1.4359x over previous
//
#include <hip/hip_runtime.h>
#include <hip/hip_bf16.h>

#define N_NODES 50000
#define N_EDGES 1600000
#define N_GRAPHS 64

// ---------- helpers ----------
__device__ __forceinline__ unsigned fenc(float x) {
    unsigned u = __float_as_uint(x);
    return (u & 0x80000000u) ? ~u : (u | 0x80000000u);
}
__device__ __forceinline__ float fdec(unsigned e) {
    return (e & 0x80000000u) ? __uint_as_float(e & 0x7fffffffu) : __uint_as_float(~e);
}

// ---------- histogram: cnt[dst] += 1 (int only; deg comes later from CSR) ----------
__global__ void hist_cnt(const int* __restrict__ dst, int* __restrict__ cnt) {
    int e = blockIdx.x * 256 + threadIdx.x;
    if (e < N_EDGES) atomicAdd(&cnt[dst[e]], 1);
}

// ---------- prefix-scan (hierarchical, 3 kernels) ----------
__global__ void block_sums(const int* __restrict__ cnt, int* __restrict__ bsum) {
    __shared__ int s[256];
    int idx = blockIdx.x * 256 + threadIdx.x;
    s[threadIdx.x] = (idx < N_NODES) ? cnt[idx] : 0;
    __syncthreads();
    for (int o = 128; o; o >>= 1) {
        if (threadIdx.x < o) s[threadIdx.x] += s[threadIdx.x + o];
        __syncthreads();
    }
    if (threadIdx.x == 0) bsum[blockIdx.x] = s[0];
}

__global__ void scan_bsums(const int* __restrict__ bsum, int* __restrict__ boff,
                           int nb, int* __restrict__ row_start_last) {
    __shared__ int s[256];
    int v = (threadIdx.x < nb) ? bsum[threadIdx.x] : 0;
    s[threadIdx.x] = v;
    __syncthreads();
    for (int o = 1; o < 256; o <<= 1) {
        int t = 0;
        if (threadIdx.x >= o) t = s[threadIdx.x - o];
        __syncthreads();
        s[threadIdx.x] += t;
        __syncthreads();
    }
    if (threadIdx.x < nb) boff[threadIdx.x] = s[threadIdx.x] - v;   // exclusive
    if (threadIdx.x == 0) *row_start_last = N_EDGES;
}

__global__ void scan_counts(const int* __restrict__ cnt, const int* __restrict__ boff,
                            int* __restrict__ row_start, int* __restrict__ cursor) {
    __shared__ int s[256];
    int idx = blockIdx.x * 256 + threadIdx.x;
    int v = (idx < N_NODES) ? cnt[idx] : 0;
    s[threadIdx.x] = v;
    __syncthreads();
    for (int o = 1; o < 256; o <<= 1) {
        int t = 0;
        if (threadIdx.x >= o) t = s[threadIdx.x - o];
        __syncthreads();
        s[threadIdx.x] += t;
        __syncthreads();
    }
    if (idx < N_NODES) {
        int ex = boff[blockIdx.x] + s[threadIdx.x] - v;   // exclusive scan
        row_start[idx] = ex;
        cursor[idx]    = ex;
    }
}

// ---------- fill CSR: packed {src, ew} sorted by dst (no dinv needed here) ----------
__global__ void fill_pack(const int* __restrict__ src, const int* __restrict__ dst,
                          const float* __restrict__ ew, int* __restrict__ cursor,
                          uint2* __restrict__ csr) {
    int e = blockIdx.x * 256 + threadIdx.x;
    if (e < N_EDGES) {
        int d = dst[e];
        int pos = atomicAdd(&cursor[d], 1);
        csr[pos] = make_uint2((unsigned)src[e], __float_as_uint(ew[e]));
    }
}

// ---------- deg/dinv from CSR rows (atomic-free segmented sum; 16 lanes per node) ----------
__global__ void deg_dinv_csr(const int* __restrict__ row_start, const uint2* __restrict__ csr,
                             float* __restrict__ dinv) {
    int t = blockIdx.x * 256 + threadIdx.x;
    int n = t >> 4;
    int l = t & 15;
    if (n >= N_NODES) return;
    int beg = row_start[n], end = row_start[n + 1];
    float s = 0.f;
    for (int i = beg + l; i < end; i += 16) s += __uint_as_float(csr[i].y);
    for (int o = 8; o; o >>= 1) s += __shfl_xor(s, o, 16);
    if (l == 0) dinv[n] = rsqrtf(s + 1.0f);
}

// ---------- GEMM1: Y(chunk-major [8][N][16]) = dinv[r] * (X[N,128] @ W[128,128]) ----------
__global__ void gemm1_reg(const float* __restrict__ X, const float* __restrict__ W,
                          const float* __restrict__ dinv, float* __restrict__ Y, int nrows) {
    __shared__ float Xl[32][132];
    __shared__ float Wl[64][128];
    const int rt = threadIdx.x >> 5;   // 0..7  (4 rows each)
    const int ct = threadIdx.x & 31;   // 0..31 (4 cols each)
    const int base = blockIdx.x * 32;
    for (int i = threadIdx.x; i < 32 * 32; i += 256) {
        int rr = i >> 5, cc = (i & 31) << 2;
        int gr = base + rr;
        float4 v = (gr < nrows) ? *(const float4*)&X[(size_t)gr * 128 + cc]
                                : make_float4(0.f, 0.f, 0.f, 0.f);
        Xl[rr][cc] = v.x; Xl[rr][cc + 1] = v.y; Xl[rr][cc + 2] = v.z; Xl[rr][cc + 3] = v.w;
    }
    float acc[4][4] = {};
    for (int kb = 0; kb < 128; kb += 64) {
        __syncthreads();
        for (int i = threadIdx.x; i < 64 * 32; i += 256) {
            int kk = i >> 5, cc = (i & 31) << 2;
            *(float4*)&Wl[kk][cc] = *(const float4*)&W[(size_t)(kb + kk) * 128 + cc];
        }
        __syncthreads();
        for (int k = 0; k < 64; k += 4) {
            float4 a0 = *(const float4*)&Xl[rt * 4 + 0][kb + k];
            float4 a1 = *(const float4*)&Xl[rt * 4 + 1][kb + k];
            float4 a2 = *(const float4*)&Xl[rt * 4 + 2][kb + k];
            float4 a3 = *(const float4*)&Xl[rt * 4 + 3][kb + k];
            float4 w0 = *(const float4*)&Wl[k + 0][ct * 4];
            float4 w1 = *(const float4*)&Wl[k + 1][ct * 4];
            float4 w2 = *(const float4*)&Wl[k + 2][ct * 4];
            float4 w3 = *(const float4*)&Wl[k + 3][ct * 4];
            #define STEP(av, wv)  \
                acc[0][0] += av##0 * wv.x; acc[0][1] += av##0 * wv.y; acc[0][2] += av##0 * wv.z; acc[0][3] += av##0 * wv.w; \
                acc[1][0] += av##1 * wv.x; acc[1][1] += av##1 * wv.y; acc[1][2] += av##1 * wv.z; acc[1][3] += av##1 * wv.w; \
                acc[2][0] += av##2 * wv.x; acc[2][1] += av##2 * wv.y; acc[2][2] += av##2 * wv.z; acc[2][3] += av##2 * wv.w; \
                acc[3][0] += av##3 * wv.x; acc[3][1] += av##3 * wv.y; acc[3][2] += av##3 * wv.z; acc[3][3] += av##3 * wv.w;
            { float ax0=a0.x, ax1=a1.x, ax2=a2.x, ax3=a3.x; STEP(ax, w0) }
            { float ay0=a0.y, ay1=a1.y, ay2=a2.y, ay3=a3.y; STEP(ay, w1) }
            { float az0=a0.z, az1=a1.z, az2=a2.z, az3=a3.z; STEP(az, w2) }
            { float aw0=a0.w, aw1=a1.w, aw2=a2.w, aw3=a3.w; STEP(aw, w3) }
            #undef STEP
        }
    }
    const int chunk = ct >> 2;
    const int ccol  = (ct & 3) * 4;
    for (int i = 0; i < 4; ++i) {
        int gr = base + rt * 4 + i;
        if (gr < nrows) {
            float dv = dinv[gr];
            float4 v = make_float4(acc[i][0] * dv, acc[i][1] * dv, acc[i][2] * dv, acc[i][3] * dv);
            *(float4*)&Y[((size_t)chunk * nrows + gr) * 16 + ccol] = v;
        }
    }
}

// ---------- GEMM2: Y(chunk-major [4][N][16]) = dinv[r] * (X[N,128] @ W[128,64]) ----------
__global__ void gemm2_reg(const float* __restrict__ X, const float* __restrict__ W,
                          const float* __restrict__ dinv, float* __restrict__ Y, int nrows) {
    __shared__ float Xl[32][132];
    __shared__ float Wl[128][64];
    const int rt = threadIdx.x >> 5;   // 0..7  (4 rows)
    const int ct = threadIdx.x & 31;   // 0..31 (2 cols)
    const int base = blockIdx.x * 32;
    for (int i = threadIdx.x; i < 32 * 32; i += 256) {
        int rr = i >> 5, cc = (i & 31) << 2;
        int gr = base + rr;
        float4 v = (gr < nrows) ? *(const float4*)&X[(size_t)gr * 128 + cc]
                                : make_float4(0.f, 0.f, 0.f, 0.f);
        Xl[rr][cc] = v.x; Xl[rr][cc + 1] = v.y; Xl[rr][cc + 2] = v.z; Xl[rr][cc + 3] = v.w;
    }
    for (int i = threadIdx.x; i < 128 * 16; i += 256) {
        int kk = i >> 4, cc = (i & 15) << 2;
        *(float4*)&Wl[kk][cc] = *(const float4*)&W[(size_t)kk * 64 + cc];
    }
    float acc[4][2] = {};
    __syncthreads();
    for (int k = 0; k < 128; k += 4) {
        float4 a0 = *(const float4*)&Xl[rt * 4 + 0][k];
        float4 a1 = *(const float4*)&Xl[rt * 4 + 1][k];
        float4 a2 = *(const float4*)&Xl[rt * 4 + 2][k];
        float4 a3 = *(const float4*)&Xl[rt * 4 + 3][k];
        float2 w0 = *(const float2*)&Wl[k + 0][ct * 2];
        float2 w1 = *(const float2*)&Wl[k + 1][ct * 2];
        float2 w2 = *(const float2*)&Wl[k + 2][ct * 2];
        float2 w3 = *(const float2*)&Wl[k + 3][ct * 2];
        acc[0][0] += a0.x * w0.x; acc[0][1] += a0.x * w0.y;
        acc[1][0] += a1.x * w0.x; acc[1][1] += a1.x * w0.y;
        acc[2][0] += a2.x * w0.x; acc[2][1] += a2.x * w0.y;
        acc[3][0] += a3.x * w0.x; acc[3][1] += a3.x * w0.y;
        acc[0][0] += a0.y * w1.x; acc[0][1] += a0.y * w1.y;
        acc[1][0] += a1.y * w1.x; acc[1][1] += a1.y * w1.y;
        acc[2][0] += a2.y * w1.x; acc[2][1] += a2.y * w1.y;
        acc[3][0] += a3.y * w1.x; acc[3][1] += a3.y * w1.y;
        acc[0][0] += a0.z * w2.x; acc[0][1] += a0.z * w2.y;
        acc[1][0] += a1.z * w2.x; acc[1][1] += a1.z * w2.y;
        acc[2][0] += a2.z * w2.x; acc[2][1] += a2.z * w2.y;
        acc[3][0] += a3.z * w2.x; acc[3][1] += a3.z * w2.y;
        acc[0][0] += a0.w * w3.x; acc[0][1] += a0.w * w3.y;
        acc[1][0] += a1.w * w3.x; acc[1][1] += a1.w * w3.y;
        acc[2][0] += a2.w * w3.x; acc[2][1] += a2.w * w3.y;
        acc[3][0] += a3.w * w3.x; acc[3][1] += a3.w * w3.y;
    }
    const int col0  = ct * 2;
    const int chunk = col0 >> 4;
    const int ccol  = col0 & 15;
    for (int i = 0; i < 4; ++i) {
        int gr = base + rt * 4 + i;
        if (gr < nrows) {
            float dv = dinv[gr];
            float2 v = make_float2(acc[i][0] * dv, acc[i][1] * dv);
            *(float2*)&Y[((size_t)chunk * nrows + gr) * 16 + ccol] = v;
        }
    }
}

// ---------- CSR aggregation from chunk-major xws, fused epilogue ----------
// out[n,kg] = relu( dinv[n] * ( sum_e ew_e * xws[src_e] + xws[n] ) + b[kg] )
template<int NC>
__global__ void agg_csr_chunk(const int* __restrict__ row_start, const uint2* __restrict__ csr,
                              const float* __restrict__ xwc, const float* __restrict__ dinv,
                              const float* __restrict__ b, float* __restrict__ out_h) {
    constexpr int OUT = NC * 16;
    const int c  = blockIdx.x % NC;
    const int nb = blockIdx.x / NC;
    const int n  = nb * 16 + (threadIdx.x >> 4);
    const int kk = threadIdx.x & 15;
    if (n >= N_NODES) return;
    const float* __restrict__ base = xwc + (size_t)c * N_NODES * 16 + kk;
    const int beg = row_start[n], end = row_start[n + 1];
    float acc = 0.f;
    int i = beg;
    for (; i + 3 < end; i += 4) {
        uint2 e0 = csr[i], e1 = csr[i + 1], e2 = csr[i + 2], e3 = csr[i + 3];
        acc += __uint_as_float(e0.y) * base[(size_t)e0.x * 16]
             + __uint_as_float(e1.y) * base[(size_t)e1.x * 16]
             + __uint_as_float(e2.y) * base[(size_t)e2.x * 16]
             + __uint_as_float(e3.y) * base[(size_t)e3.x * 16];
    }
    for (; i < end; ++i) acc += __uint_as_float(csr[i].y) * base[(size_t)csr[i].x * 16];
    int kg = c * 16 + kk;
    float v = dinv[n] * (acc + base[(size_t)n * 16]) + b[kg];
    out_h[(size_t)n * OUT + kg] = fmaxf(v, 0.f);
}

// ---------- gate ----------
__global__ void gate_kernel(const float* __restrict__ x1, const float* __restrict__ gW1,
                            const float* __restrict__ gb1, const float* __restrict__ gW2,
                            const float* __restrict__ gb2, const int* __restrict__ batch,
                            float* __restrict__ g, unsigned* __restrict__ gmax_enc) {
    __shared__ float W1l[64 * 32];
    __shared__ float W2l[32];
    __shared__ float b1l[32];
    for (int i = threadIdx.x; i < 64 * 32; i += 256) W1l[i] = gW1[i];
    if (threadIdx.x < 32) { W2l[threadIdx.x] = gW2[threadIdx.x]; b1l[threadIdx.x] = gb1[threadIdx.x]; }
    __syncthreads();
    const float gb2v = gb2[0];
    int n = blockIdx.x * 256 + threadIdx.x;
    bool act = (n < N_NODES);
    float gv = -1e30f;
    int b = 0;
    if (act) {
        const float* row = x1 + (size_t)n * 64;
        float t[32];
        #pragma unroll
        for (int j = 0; j < 32; ++j) t[j] = b1l[j];
        for (int k = 0; k < 64; ++k) {
            float xv = row[k];
            #pragma unroll
            for (int j = 0; j < 32; ++j) t[j] += xv * W1l[k * 32 + j];
        }
        float a = gb2v;
        #pragma unroll
        for (int j = 0; j < 32; ++j) a += fmaxf(t[j], 0.f) * W2l[j];
        gv = a;
        g[n] = a;
        b = batch[n];
    }
    unsigned long long actm = __ballot(act);
    int b0 = __shfl(b, 0);
    bool uniform = (actm == ~0ull) && (__ballot(b == b0) == ~0ull);
    if (uniform) {
        float m = gv;
        for (int o = 32; o; o >>= 1) m = fmaxf(m, __shfl_xor(m, o));
        if ((threadIdx.x & 63) == 0) atomicMax(&gmax_enc[b0], fenc(m));
    } else if (act) {
        atomicMax(&gmax_enc[b], fenc(gv));
    }
}

__global__ void exp_kernel(const float* __restrict__ g, const int* __restrict__ batch,
                           const unsigned* __restrict__ gmax_enc, float* __restrict__ ex,
                           float* __restrict__ den) {
    int n = blockIdx.x * 256 + threadIdx.x;
    bool act = (n < N_NODES);
    float v = 0.f; int b = 0;
    if (act) {
        b = batch[n];
        v = expf(g[n] - fdec(gmax_enc[b]));
        ex[n] = v;
    }
    unsigned long long actm = __ballot(act);
    int b0 = __shfl(b, 0);
    bool uniform = (actm == ~0ull) && (__ballot(b == b0) == ~0ull);
    if (uniform) {
        float s = v;
        for (int o = 32; o; o >>= 1) s += __shfl_xor(s, o);
        if ((threadIdx.x & 63) == 0) atomicAdd(&den[b0], s);
    } else if (act) {
        atomicAdd(&den[b], v);
    }
}

__global__ void alpha_kernel(float* __restrict__ ex, const int* __restrict__ batch,
                             const float* __restrict__ den) {
    int n = blockIdx.x * 256 + threadIdx.x;
    if (n < N_NODES) ex[n] = ex[n] / den[batch[n]];
}

__global__ void pool_kernel(const float* __restrict__ x1, const float* __restrict__ alpha,
                            const int* __restrict__ batch, float* __restrict__ pooled) {
    const int L = 32;
    const int f   = threadIdx.x & 63;
    const int grp = threadIdx.x >> 6;
    int chunk = blockIdx.x * 4 + grp;
    int start = chunk * L;
    if (start >= N_NODES) return;
    int end = min(start + L, N_NODES);
    int cur = batch[start];
    float acc = 0.f;
    for (int n = start; n < end; ++n) {
        int bb = batch[n];
        if (bb != cur) { atomicAdd(&pooled[cur * 64 + f], acc); acc = 0.f; cur = bb; }
        acc += alpha[n] * x1[(size_t)n * 64 + f];
    }
    atomicAdd(&pooled[cur * 64 + f], acc);
}

__global__ void head_kernel(const float* __restrict__ pooled, const float* __restrict__ fcW1,
                            const float* __restrict__ fcb1, const float* __restrict__ fcW2,
                            const float* __restrict__ fcb2, float* __restrict__ out) {
    __shared__ float P[64 * 64];
    __shared__ float W1l[64 * 128];
    __shared__ float H[64 * 128];
    for (int i = threadIdx.x; i < 64 * 64; i += 256) P[i] = pooled[i];
    for (int i = threadIdx.x; i < 64 * 128; i += 256) W1l[i] = fcW1[i];
    __syncthreads();
    for (int i = threadIdx.x; i < 64 * 128; i += 256) {
        int gi = i >> 7, j = i & 127;
        float a = fcb1[j];
        for (int k = 0; k < 64; ++k) a += P[gi * 64 + k] * W1l[k * 128 + j];
        H[i] = fmaxf(a, 0.f);
    }
    __syncthreads();
    if (threadIdx.x < 64) {
        int gi = threadIdx.x;
        float l0 = fcb2[0], l1 = fcb2[1];
        for (int k = 0; k < 128; ++k) {
            float h = H[gi * 128 + k];
            l0 += h * fcW2[k * 2 + 0];
            l1 += h * fcW2[k * 2 + 1];
        }
        float m = fmaxf(l0, l1);
        float lse = m + logf(expf(l0 - m) + expf(l1 - m));
        out[gi * 2 + 0] = l0 - lse;
        out[gi * 2 + 1] = l1 - lse;
    }
}

extern "C" void kernel_launch(void* const* d_in, const int* in_sizes, int n_in,
                              void* d_out, int out_size, void* d_ws, size_t ws_size,
                              hipStream_t stream) {
    const float* x    = (const float*)d_in[0];
    const int*   ei   = (const int*)d_in[1];
    const float* ew   = (const float*)d_in[2];
    const int*   batch= (const int*)d_in[3];
    const float* W1   = (const float*)d_in[4];
    const float* b1   = (const float*)d_in[5];
    const float* W2   = (const float*)d_in[6];
    const float* b2   = (const float*)d_in[7];
    const float* gW1  = (const float*)d_in[8];
    const float* gb1  = (const float*)d_in[9];
    const float* gW2  = (const float*)d_in[10];
    const float* gb2  = (const float*)d_in[11];
    const float* fcW1 = (const float*)d_in[12];
    const float* fcb1 = (const float*)d_in[13];
    const float* fcW2 = (const float*)d_in[14];
    const float* fcb2 = (const float*)d_in[15];
    float* out = (float*)d_out;

    const int* src = ei;
    const int* dst = ei + N_EDGES;

    const int EB = (N_EDGES + 255) / 256;          // 6250
    const int NB = (N_NODES + 255) / 256;          // 196
    const int NBLK16 = (N_NODES + 15) / 16;        // 3125

    // ---- workspace layout (floats) ----
    float* ws = (float*)d_ws;
    float* xw    = ws;                             // 6,400,000 (chunk-major [NC][N][16], dinv-scaled)
    float* agg   = ws + 6400000;                   // 6,400,000 (row-major h / x1)
    size_t off = 12800000;
    uint2* csr      = (uint2*)(ws + off);  off += 3200000;   // packed {src, ew}
    int*   row_start= (int*)(ws + off);    off += 50176;
    int*   cnt      = (int*)(ws + off);    off += 50176;
    int*   cursor   = (int*)(ws + off);    off += 50176;
    float* dinv     = ws + off;            off += 50176;
    float* g        = ws + off;            off += 50048;
    float* ex       = ws + off;            off += 50048;
    int*   bsum     = (int*)(ws + off);    off += 256;
    int*   boff     = (int*)(ws + off);    off += 256;
    unsigned* gmax  = (unsigned*)(ws + off); off += 64;
    float* den      = ws + off;            off += 64;
    float* pooled   = ws + off;            off += 4096;

    // ---- CSR build ----
    hipMemsetAsync(cnt, 0, N_NODES * sizeof(int), stream);
    hist_cnt<<<EB, 256, 0, stream>>>(dst, cnt);
    block_sums<<<NB, 256, 0, stream>>>(cnt, bsum);
    scan_bsums<<<1, 256, 0, stream>>>(bsum, boff, NB, row_start + N_NODES);
    scan_counts<<<NB, 256, 0, stream>>>(cnt, boff, row_start, cursor);
    fill_pack<<<EB, 256, 0, stream>>>(src, dst, ew, cursor, csr);
    deg_dinv_csr<<<NBLK16, 256, 0, stream>>>(row_start, csr, dinv);

    // ---- conv1 ----
    gemm1_reg<<<(N_NODES + 31) / 32, 256, 0, stream>>>(x, W1, dinv, xw, N_NODES);
    agg_csr_chunk<8><<<8 * NBLK16, 256, 0, stream>>>(row_start, csr, xw, dinv, b1, agg);

    // ---- conv2 ----
    gemm2_reg<<<(N_NODES + 31) / 32, 256, 0, stream>>>(agg, W2, dinv, xw, N_NODES);
    agg_csr_chunk<4><<<4 * NBLK16, 256, 0, stream>>>(row_start, csr, xw, dinv, b2, agg);

    // ---- global attention ----
    hipMemsetAsync(gmax, 0, N_GRAPHS * sizeof(unsigned), stream);
    hipMemsetAsync(den, 0, N_GRAPHS * sizeof(float), stream);
    hipMemsetAsync(pooled, 0, N_GRAPHS * 64 * sizeof(float), stream);
    gate_kernel<<<NB, 256, 0, stream>>>(agg, gW1, gb1, gW2, gb2, batch, g, gmax);
    exp_kernel<<<NB, 256, 0, stream>>>(g, batch, gmax, ex, den);
    alpha_kernel<<<NB, 256, 0, stream>>>(ex, batch, den);
    int nchunks = (N_NODES + 31) / 32;
    pool_kernel<<<(nchunks + 3) / 4, 256, 0, stream>>>(agg, ex, batch, pooled);

    // ---- head ----
    head_kernel<<<1, 256, 0, stream>>>(pooled, fcW1, fcb1, fcW2, fcb2, out);
}

// Round 6
// 601.537 us; speedup vs baseline: 1.5256x; 1.0625x over previous
//
#include <hip/hip_runtime.h>
#include <hip/hip_bf16.h>
#include <hip/hip_fp16.h>

#define N_NODES 50000
#define N_EDGES 1600000
#define N_GRAPHS 64

// ---------- helpers ----------
__device__ __forceinline__ unsigned fenc(float x) {
    unsigned u = __float_as_uint(x);
    return (u & 0x80000000u) ? ~u : (u | 0x80000000u);
}
__device__ __forceinline__ float fdec(unsigned e) {
    return (e & 0x80000000u) ? __uint_as_float(e & 0x7fffffffu) : __uint_as_float(~e);
}
__device__ __forceinline__ float ew_of(unsigned p) {
    return __half2float(__ushort_as_half((unsigned short)(p & 0xFFFFu)));
}

// ---------- histogram: cnt[dst] += 1 ----------
__global__ void hist_cnt(const int* __restrict__ dst, int* __restrict__ cnt) {
    int e = blockIdx.x * 256 + threadIdx.x;
    if (e < N_EDGES) atomicAdd(&cnt[dst[e]], 1);
}

// ---------- prefix-scan (hierarchical, 3 kernels) ----------
__global__ void block_sums(const int* __restrict__ cnt, int* __restrict__ bsum) {
    __shared__ int s[256];
    int idx = blockIdx.x * 256 + threadIdx.x;
    s[threadIdx.x] = (idx < N_NODES) ? cnt[idx] : 0;
    __syncthreads();
    for (int o = 128; o; o >>= 1) {
        if (threadIdx.x < o) s[threadIdx.x] += s[threadIdx.x + o];
        __syncthreads();
    }
    if (threadIdx.x == 0) bsum[blockIdx.x] = s[0];
}

__global__ void scan_bsums(const int* __restrict__ bsum, int* __restrict__ boff,
                           int nb, int* __restrict__ row_start_last) {
    __shared__ int s[256];
    int v = (threadIdx.x < nb) ? bsum[threadIdx.x] : 0;
    s[threadIdx.x] = v;
    __syncthreads();
    for (int o = 1; o < 256; o <<= 1) {
        int t = 0;
        if (threadIdx.x >= o) t = s[threadIdx.x - o];
        __syncthreads();
        s[threadIdx.x] += t;
        __syncthreads();
    }
    if (threadIdx.x < nb) boff[threadIdx.x] = s[threadIdx.x] - v;   // exclusive
    if (threadIdx.x == 0) *row_start_last = N_EDGES;
}

__global__ void scan_counts(const int* __restrict__ cnt, const int* __restrict__ boff,
                            int* __restrict__ row_start, int* __restrict__ cursor) {
    __shared__ int s[256];
    int idx = blockIdx.x * 256 + threadIdx.x;
    int v = (idx < N_NODES) ? cnt[idx] : 0;
    s[threadIdx.x] = v;
    __syncthreads();
    for (int o = 1; o < 256; o <<= 1) {
        int t = 0;
        if (threadIdx.x >= o) t = s[threadIdx.x - o];
        __syncthreads();
        s[threadIdx.x] += t;
        __syncthreads();
    }
    if (idx < N_NODES) {
        int ex = boff[blockIdx.x] + s[threadIdx.x] - v;   // exclusive scan
        row_start[idx] = ex;
        cursor[idx]    = ex;
    }
}

// ---------- fill CSR: packed (src<<16 | f16(ew)) sorted by dst ----------
__global__ void fill_pack(const int* __restrict__ src, const int* __restrict__ dst,
                          const float* __restrict__ ew, int* __restrict__ cursor,
                          unsigned* __restrict__ csr) {
    int e = blockIdx.x * 256 + threadIdx.x;
    if (e < N_EDGES) {
        int d = dst[e];
        unsigned short hb = __half_as_ushort(__float2half(ew[e]));
        int pos = atomicAdd(&cursor[d], 1);
        csr[pos] = ((unsigned)src[e] << 16) | (unsigned)hb;
    }
}

// ---------- deg/dinv from CSR rows (atomic-free segmented sum; 16 lanes/node) ----------
__global__ void deg_dinv_csr(const int* __restrict__ row_start, const unsigned* __restrict__ csr,
                             float* __restrict__ dinv) {
    int t = blockIdx.x * 256 + threadIdx.x;
    int n = t >> 4;
    int l = t & 15;
    if (n >= N_NODES) return;
    int beg = row_start[n], end = row_start[n + 1];
    float s = 0.f;
    for (int i = beg + l; i < end; i += 16) s += ew_of(csr[i]);
    for (int o = 8; o; o >>= 1) s += __shfl_xor(s, o, 16);
    if (l == 0) dinv[n] = rsqrtf(s + 1.0f);
}

// ---------- GEMM1: Y(chunk-major [8][N][16]) = dinv[r] * (X[N,128] @ W[128,128]) ----------
__global__ void gemm1_reg(const float* __restrict__ X, const float* __restrict__ W,
                          const float* __restrict__ dinv, float* __restrict__ Y, int nrows) {
    __shared__ float Xl[32][132];
    __shared__ float Wl[64][128];
    const int rt = threadIdx.x >> 5;   // 0..7  (4 rows each)
    const int ct = threadIdx.x & 31;   // 0..31 (4 cols each)
    const int base = blockIdx.x * 32;
    for (int i = threadIdx.x; i < 32 * 32; i += 256) {
        int rr = i >> 5, cc = (i & 31) << 2;
        int gr = base + rr;
        float4 v = (gr < nrows) ? *(const float4*)&X[(size_t)gr * 128 + cc]
                                : make_float4(0.f, 0.f, 0.f, 0.f);
        Xl[rr][cc] = v.x; Xl[rr][cc + 1] = v.y; Xl[rr][cc + 2] = v.z; Xl[rr][cc + 3] = v.w;
    }
    float acc[4][4] = {};
    for (int kb = 0; kb < 128; kb += 64) {
        __syncthreads();
        for (int i = threadIdx.x; i < 64 * 32; i += 256) {
            int kk = i >> 5, cc = (i & 31) << 2;
            *(float4*)&Wl[kk][cc] = *(const float4*)&W[(size_t)(kb + kk) * 128 + cc];
        }
        __syncthreads();
        for (int k = 0; k < 64; k += 4) {
            float4 a0 = *(const float4*)&Xl[rt * 4 + 0][kb + k];
            float4 a1 = *(const float4*)&Xl[rt * 4 + 1][kb + k];
            float4 a2 = *(const float4*)&Xl[rt * 4 + 2][kb + k];
            float4 a3 = *(const float4*)&Xl[rt * 4 + 3][kb + k];
            float4 w0 = *(const float4*)&Wl[k + 0][ct * 4];
            float4 w1 = *(const float4*)&Wl[k + 1][ct * 4];
            float4 w2 = *(const float4*)&Wl[k + 2][ct * 4];
            float4 w3 = *(const float4*)&Wl[k + 3][ct * 4];
            #define STEP(av, wv)  \
                acc[0][0] += av##0 * wv.x; acc[0][1] += av##0 * wv.y; acc[0][2] += av##0 * wv.z; acc[0][3] += av##0 * wv.w; \
                acc[1][0] += av##1 * wv.x; acc[1][1] += av##1 * wv.y; acc[1][2] += av##1 * wv.z; acc[1][3] += av##1 * wv.w; \
                acc[2][0] += av##2 * wv.x; acc[2][1] += av##2 * wv.y; acc[2][2] += av##2 * wv.z; acc[2][3] += av##2 * wv.w; \
                acc[3][0] += av##3 * wv.x; acc[3][1] += av##3 * wv.y; acc[3][2] += av##3 * wv.z; acc[3][3] += av##3 * wv.w;
            { float ax0=a0.x, ax1=a1.x, ax2=a2.x, ax3=a3.x; STEP(ax, w0) }
            { float ay0=a0.y, ay1=a1.y, ay2=a2.y, ay3=a3.y; STEP(ay, w1) }
            { float az0=a0.z, az1=a1.z, az2=a2.z, az3=a3.z; STEP(az, w2) }
            { float aw0=a0.w, aw1=a1.w, aw2=a2.w, aw3=a3.w; STEP(aw, w3) }
            #undef STEP
        }
    }
    const int chunk = ct >> 2;
    const int ccol  = (ct & 3) * 4;
    for (int i = 0; i < 4; ++i) {
        int gr = base + rt * 4 + i;
        if (gr < nrows) {
            float dv = dinv[gr];
            float4 v = make_float4(acc[i][0] * dv, acc[i][1] * dv, acc[i][2] * dv, acc[i][3] * dv);
            *(float4*)&Y[((size_t)chunk * nrows + gr) * 16 + ccol] = v;
        }
    }
}

// ---------- GEMM2: Y(chunk-major [4][N][16]) = dinv[r] * (X[N,128] @ W[128,64]) ----------
__global__ void gemm2_reg(const float* __restrict__ X, const float* __restrict__ W,
                          const float* __restrict__ dinv, float* __restrict__ Y, int nrows) {
    __shared__ float Xl[32][132];
    __shared__ float Wl[128][64];
    const int rt = threadIdx.x >> 5;   // 0..7  (4 rows)
    const int ct = threadIdx.x & 31;   // 0..31 (2 cols)
    const int base = blockIdx.x * 32;
    for (int i = threadIdx.x; i < 32 * 32; i += 256) {
        int rr = i >> 5, cc = (i & 31) << 2;
        int gr = base + rr;
        float4 v = (gr < nrows) ? *(const float4*)&X[(size_t)gr * 128 + cc]
                                : make_float4(0.f, 0.f, 0.f, 0.f);
        Xl[rr][cc] = v.x; Xl[rr][cc + 1] = v.y; Xl[rr][cc + 2] = v.z; Xl[rr][cc + 3] = v.w;
    }
    for (int i = threadIdx.x; i < 128 * 16; i += 256) {
        int kk = i >> 4, cc = (i & 15) << 2;
        *(float4*)&Wl[kk][cc] = *(const float4*)&W[(size_t)kk * 64 + cc];
    }
    float acc[4][2] = {};
    __syncthreads();
    for (int k = 0; k < 128; k += 4) {
        float4 a0 = *(const float4*)&Xl[rt * 4 + 0][k];
        float4 a1 = *(const float4*)&Xl[rt * 4 + 1][k];
        float4 a2 = *(const float4*)&Xl[rt * 4 + 2][k];
        float4 a3 = *(const float4*)&Xl[rt * 4 + 3][k];
        float2 w0 = *(const float2*)&Wl[k + 0][ct * 2];
        float2 w1 = *(const float2*)&Wl[k + 1][ct * 2];
        float2 w2 = *(const float2*)&Wl[k + 2][ct * 2];
        float2 w3 = *(const float2*)&Wl[k + 3][ct * 2];
        acc[0][0] += a0.x * w0.x; acc[0][1] += a0.x * w0.y;
        acc[1][0] += a1.x * w0.x; acc[1][1] += a1.x * w0.y;
        acc[2][0] += a2.x * w0.x; acc[2][1] += a2.x * w0.y;
        acc[3][0] += a3.x * w0.x; acc[3][1] += a3.x * w0.y;
        acc[0][0] += a0.y * w1.x; acc[0][1] += a0.y * w1.y;
        acc[1][0] += a1.y * w1.x; acc[1][1] += a1.y * w1.y;
        acc[2][0] += a2.y * w1.x; acc[2][1] += a2.y * w1.y;
        acc[3][0] += a3.y * w1.x; acc[3][1] += a3.y * w1.y;
        acc[0][0] += a0.z * w2.x; acc[0][1] += a0.z * w2.y;
        acc[1][0] += a1.z * w2.x; acc[1][1] += a1.z * w2.y;
        acc[2][0] += a2.z * w2.x; acc[2][1] += a2.z * w2.y;
        acc[3][0] += a3.z * w2.x; acc[3][1] += a3.z * w2.y;
        acc[0][0] += a0.w * w3.x; acc[0][1] += a0.w * w3.y;
        acc[1][0] += a1.w * w3.x; acc[1][1] += a1.w * w3.y;
        acc[2][0] += a2.w * w3.x; acc[2][1] += a2.w * w3.y;
        acc[3][0] += a3.w * w3.x; acc[3][1] += a3.w * w3.y;
    }
    const int col0  = ct * 2;
    const int chunk = col0 >> 4;
    const int ccol  = col0 & 15;
    for (int i = 0; i < 4; ++i) {
        int gr = base + rt * 4 + i;
        if (gr < nrows) {
            float dv = dinv[gr];
            float2 v = make_float2(acc[i][0] * dv, acc[i][1] * dv);
            *(float2*)&Y[((size_t)chunk * nrows + gr) * 16 + ccol] = v;
        }
    }
}

// ---------- CSR aggregation: 32 lanes/node (16 feats x even/odd edges) ----------
// out[n,kg] = relu( dinv[n] * ( sum_e ew_e * xws[src_e] + xws[n] ) + b[kg] )
template<int NC>
__global__ void agg_csr_chunk(const int* __restrict__ row_start, const unsigned* __restrict__ csr,
                              const float* __restrict__ xwc, const float* __restrict__ dinv,
                              const float* __restrict__ b, float* __restrict__ out_h) {
    constexpr int OUT = NC * 16;
    const int c    = blockIdx.x % NC;
    const int nb   = blockIdx.x / NC;
    const int n    = nb * 8 + (threadIdx.x >> 5);
    const int kk   = threadIdx.x & 15;
    const int half = (threadIdx.x >> 4) & 1;
    if (n >= N_NODES) return;
    const float* __restrict__ base = xwc + (size_t)c * N_NODES * 16 + kk;
    const int beg = row_start[n], end = row_start[n + 1];
    float acc = 0.f;
    int i = beg + half;
    for (; i + 6 < end; i += 8) {       // this half: i, i+2, i+4, i+6
        unsigned p0 = csr[i],     p1 = csr[i + 2];
        unsigned p2 = csr[i + 4], p3 = csr[i + 6];
        acc += ew_of(p0) * base[(size_t)(p0 >> 16) * 16]
             + ew_of(p1) * base[(size_t)(p1 >> 16) * 16]
             + ew_of(p2) * base[(size_t)(p2 >> 16) * 16]
             + ew_of(p3) * base[(size_t)(p3 >> 16) * 16];
    }
    for (; i < end; i += 2) {
        unsigned p = csr[i];
        acc += ew_of(p) * base[(size_t)(p >> 16) * 16];
    }
    acc += __shfl_xor(acc, 16);         // merge even/odd halves
    if (half == 0) {
        int kg = c * 16 + kk;
        float v = dinv[n] * (acc + base[(size_t)n * 16]) + b[kg];
        out_h[(size_t)n * OUT + kg] = fmaxf(v, 0.f);
    }
}

// ---------- gate ----------
__global__ void gate_kernel(const float* __restrict__ x1, const float* __restrict__ gW1,
                            const float* __restrict__ gb1, const float* __restrict__ gW2,
                            const float* __restrict__ gb2, const int* __restrict__ batch,
                            float* __restrict__ g, unsigned* __restrict__ gmax_enc) {
    __shared__ float W1l[64 * 32];
    __shared__ float W2l[32];
    __shared__ float b1l[32];
    for (int i = threadIdx.x; i < 64 * 32; i += 256) W1l[i] = gW1[i];
    if (threadIdx.x < 32) { W2l[threadIdx.x] = gW2[threadIdx.x]; b1l[threadIdx.x] = gb1[threadIdx.x]; }
    __syncthreads();
    const float gb2v = gb2[0];
    int n = blockIdx.x * 256 + threadIdx.x;
    bool act = (n < N_NODES);
    float gv = -1e30f;
    int b = 0;
    if (act) {
        const float* row = x1 + (size_t)n * 64;
        float t[32];
        #pragma unroll
        for (int j = 0; j < 32; ++j) t[j] = b1l[j];
        for (int k = 0; k < 64; ++k) {
            float xv = row[k];
            #pragma unroll
            for (int j = 0; j < 32; ++j) t[j] += xv * W1l[k * 32 + j];
        }
        float a = gb2v;
        #pragma unroll
        for (int j = 0; j < 32; ++j) a += fmaxf(t[j], 0.f) * W2l[j];
        gv = a;
        g[n] = a;
        b = batch[n];
    }
    unsigned long long actm = __ballot(act);
    int b0 = __shfl(b, 0);
    bool uniform = (actm == ~0ull) && (__ballot(b == b0) == ~0ull);
    if (uniform) {
        float m = gv;
        for (int o = 32; o; o >>= 1) m = fmaxf(m, __shfl_xor(m, o));
        if ((threadIdx.x & 63) == 0) atomicMax(&gmax_enc[b0], fenc(m));
    } else if (act) {
        atomicMax(&gmax_enc[b], fenc(gv));
    }
}

__global__ void exp_kernel(const float* __restrict__ g, const int* __restrict__ batch,
                           const unsigned* __restrict__ gmax_enc, float* __restrict__ ex,
                           float* __restrict__ den) {
    int n = blockIdx.x * 256 + threadIdx.x;
    bool act = (n < N_NODES);
    float v = 0.f; int b = 0;
    if (act) {
        b = batch[n];
        v = expf(g[n] - fdec(gmax_enc[b]));
        ex[n] = v;
    }
    unsigned long long actm = __ballot(act);
    int b0 = __shfl(b, 0);
    bool uniform = (actm == ~0ull) && (__ballot(b == b0) == ~0ull);
    if (uniform) {
        float s = v;
        for (int o = 32; o; o >>= 1) s += __shfl_xor(s, o);
        if ((threadIdx.x & 63) == 0) atomicAdd(&den[b0], s);
    } else if (act) {
        atomicAdd(&den[b], v);
    }
}

// ---------- pooled[batch] += (ex/den[batch]) * x1 (alpha fused; batch sorted) ----------
__global__ void pool_kernel(const float* __restrict__ x1, const float* __restrict__ ex,
                            const float* __restrict__ den, const int* __restrict__ batch,
                            float* __restrict__ pooled) {
    const int L = 32;
    const int f   = threadIdx.x & 63;
    const int grp = threadIdx.x >> 6;
    int chunk = blockIdx.x * 4 + grp;
    int start = chunk * L;
    if (start >= N_NODES) return;
    int end = min(start + L, N_NODES);
    int cur = batch[start];
    float rden = 1.f / den[cur];
    float acc = 0.f;
    for (int n = start; n < end; ++n) {
        int bb = batch[n];
        if (bb != cur) {
            atomicAdd(&pooled[cur * 64 + f], acc);
            acc = 0.f; cur = bb; rden = 1.f / den[cur];
        }
        acc += ex[n] * rden * x1[(size_t)n * 64 + f];
    }
    atomicAdd(&pooled[cur * 64 + f], acc);
}

__global__ void head_kernel(const float* __restrict__ pooled, const float* __restrict__ fcW1,
                            const float* __restrict__ fcb1, const float* __restrict__ fcW2,
                            const float* __restrict__ fcb2, float* __restrict__ out) {
    __shared__ float P[64 * 64];
    __shared__ float W1l[64 * 128];
    __shared__ float H[64 * 128];
    for (int i = threadIdx.x; i < 64 * 64; i += 256) P[i] = pooled[i];
    for (int i = threadIdx.x; i < 64 * 128; i += 256) W1l[i] = fcW1[i];
    __syncthreads();
    for (int i = threadIdx.x; i < 64 * 128; i += 256) {
        int gi = i >> 7, j = i & 127;
        float a = fcb1[j];
        for (int k = 0; k < 64; ++k) a += P[gi * 64 + k] * W1l[k * 128 + j];
        H[i] = fmaxf(a, 0.f);
    }
    __syncthreads();
    if (threadIdx.x < 64) {
        int gi = threadIdx.x;
        float l0 = fcb2[0], l1 = fcb2[1];
        for (int k = 0; k < 128; ++k) {
            float h = H[gi * 128 + k];
            l0 += h * fcW2[k * 2 + 0];
            l1 += h * fcW2[k * 2 + 1];
        }
        float m = fmaxf(l0, l1);
        float lse = m + logf(expf(l0 - m) + expf(l1 - m));
        out[gi * 2 + 0] = l0 - lse;
        out[gi * 2 + 1] = l1 - lse;
    }
}

extern "C" void kernel_launch(void* const* d_in, const int* in_sizes, int n_in,
                              void* d_out, int out_size, void* d_ws, size_t ws_size,
                              hipStream_t stream) {
    const float* x    = (const float*)d_in[0];
    const int*   ei   = (const int*)d_in[1];
    const float* ew   = (const float*)d_in[2];
    const int*   batch= (const int*)d_in[3];
    const float* W1   = (const float*)d_in[4];
    const float* b1   = (const float*)d_in[5];
    const float* W2   = (const float*)d_in[6];
    const float* b2   = (const float*)d_in[7];
    const float* gW1  = (const float*)d_in[8];
    const float* gb1  = (const float*)d_in[9];
    const float* gW2  = (const float*)d_in[10];
    const float* gb2  = (const float*)d_in[11];
    const float* fcW1 = (const float*)d_in[12];
    const float* fcb1 = (const float*)d_in[13];
    const float* fcW2 = (const float*)d_in[14];
    const float* fcb2 = (const float*)d_in[15];
    float* out = (float*)d_out;

    const int* src = ei;
    const int* dst = ei + N_EDGES;

    const int EB = (N_EDGES + 255) / 256;          // 6250
    const int NB = (N_NODES + 255) / 256;          // 196
    const int NBLK8  = (N_NODES + 7) / 8;          // 6250
    const int NBLK16 = (N_NODES + 15) / 16;        // 3125

    // ---- workspace layout (floats) ----
    float* ws = (float*)d_ws;
    float* xw    = ws;                             // 6,400,000 (chunk-major [NC][N][16], dinv-scaled)
    float* agg   = ws + 6400000;                   // 6,400,000 (row-major h / x1)
    size_t off = 12800000;
    unsigned* csr   = (unsigned*)(ws + off); off += 1600000;  // packed (src<<16 | f16 ew)
    int*   row_start= (int*)(ws + off);    off += 50176;
    int*   cnt      = (int*)(ws + off);    off += 50176;
    int*   cursor   = (int*)(ws + off);    off += 50176;
    float* dinv     = ws + off;            off += 50176;
    float* g        = ws + off;            off += 50048;
    float* ex       = ws + off;            off += 50048;
    int*   bsum     = (int*)(ws + off);    off += 256;
    int*   boff     = (int*)(ws + off);    off += 256;
    unsigned* gmax  = (unsigned*)(ws + off); off += 64;
    float* den      = ws + off;            off += 64;
    float* pooled   = ws + off;            off += 4096;

    // ---- CSR build ----
    hipMemsetAsync(cnt, 0, N_NODES * sizeof(int), stream);
    hist_cnt<<<EB, 256, 0, stream>>>(dst, cnt);
    block_sums<<<NB, 256, 0, stream>>>(cnt, bsum);
    scan_bsums<<<1, 256, 0, stream>>>(bsum, boff, NB, row_start + N_NODES);
    scan_counts<<<NB, 256, 0, stream>>>(cnt, boff, row_start, cursor);
    fill_pack<<<EB, 256, 0, stream>>>(src, dst, ew, cursor, csr);
    deg_dinv_csr<<<NBLK16, 256, 0, stream>>>(row_start, csr, dinv);

    // ---- conv1 ----
    gemm1_reg<<<(N_NODES + 31) / 32, 256, 0, stream>>>(x, W1, dinv, xw, N_NODES);
    agg_csr_chunk<8><<<8 * NBLK8, 256, 0, stream>>>(row_start, csr, xw, dinv, b1, agg);

    // ---- conv2 ----
    gemm2_reg<<<(N_NODES + 31) / 32, 256, 0, stream>>>(agg, W2, dinv, xw, N_NODES);
    agg_csr_chunk<4><<<4 * NBLK8, 256, 0, stream>>>(row_start, csr, xw, dinv, b2, agg);

    // ---- global attention ----
    hipMemsetAsync(gmax, 0, N_GRAPHS * sizeof(unsigned), stream);
    hipMemsetAsync(den, 0, N_GRAPHS * sizeof(float), stream);
    hipMemsetAsync(pooled, 0, N_GRAPHS * 64 * sizeof(float), stream);
    gate_kernel<<<NB, 256, 0, stream>>>(agg, gW1, gb1, gW2, gb2, batch, g, gmax);
    exp_kernel<<<NB, 256, 0, stream>>>(g, batch, gmax, ex, den);
    int nchunks = (N_NODES + 31) / 32;
    pool_kernel<<<(nchunks + 3) / 4, 256, 0, stream>>>(agg, ex, den, batch, pooled);

    // ---- head ----
    head_kernel<<<1, 256, 0, stream>>>(pooled, fcW1, fcb1, fcW2, fcb2, out);
}

// Round 7
// 424.212 us; speedup vs baseline: 2.1633x; 1.4180x over previous
//
#include <hip/hip_runtime.h>
#include <hip/hip_bf16.h>
#include <hip/hip_fp16.h>

#define N_NODES 50000
#define N_EDGES 1600000
#define N_GRAPHS 64

// ---------- helpers ----------
__device__ __forceinline__ unsigned fenc(float x) {
    unsigned u = __float_as_uint(x);
    return (u & 0x80000000u) ? ~u : (u | 0x80000000u);
}
__device__ __forceinline__ float fdec(unsigned e) {
    return (e & 0x80000000u) ? __uint_as_float(e & 0x7fffffffu) : __uint_as_float(~e);
}
__device__ __forceinline__ float ew_of(unsigned p) {
    return __half2float(__ushort_as_half((unsigned short)(p & 0xFFFFu)));
}

// ---------- hist: pos[e] = old count (single atomic pass) ----------
__global__ void hist_pos(const int* __restrict__ dst, int* __restrict__ cnt,
                         int* __restrict__ pos) {
    int e = blockIdx.x * 256 + threadIdx.x;
    if (e < N_EDGES) pos[e] = atomicAdd(&cnt[dst[e]], 1);
}

// ---------- prefix-scan (hierarchical, 3 kernels) ----------
__global__ void block_sums(const int* __restrict__ cnt, int* __restrict__ bsum) {
    __shared__ int s[256];
    int idx = blockIdx.x * 256 + threadIdx.x;
    s[threadIdx.x] = (idx < N_NODES) ? cnt[idx] : 0;
    __syncthreads();
    for (int o = 128; o; o >>= 1) {
        if (threadIdx.x < o) s[threadIdx.x] += s[threadIdx.x + o];
        __syncthreads();
    }
    if (threadIdx.x == 0) bsum[blockIdx.x] = s[0];
}

__global__ void scan_bsums(const int* __restrict__ bsum, int* __restrict__ boff,
                           int nb, int* __restrict__ row_start_last) {
    __shared__ int s[256];
    int v = (threadIdx.x < nb) ? bsum[threadIdx.x] : 0;
    s[threadIdx.x] = v;
    __syncthreads();
    for (int o = 1; o < 256; o <<= 1) {
        int t = 0;
        if (threadIdx.x >= o) t = s[threadIdx.x - o];
        __syncthreads();
        s[threadIdx.x] += t;
        __syncthreads();
    }
    if (threadIdx.x < nb) boff[threadIdx.x] = s[threadIdx.x] - v;   // exclusive
    if (threadIdx.x == 0) *row_start_last = N_EDGES;
}

__global__ void scan_counts(const int* __restrict__ cnt, const int* __restrict__ boff,
                            int* __restrict__ row_start) {
    __shared__ int s[256];
    int idx = blockIdx.x * 256 + threadIdx.x;
    int v = (idx < N_NODES) ? cnt[idx] : 0;
    s[threadIdx.x] = v;
    __syncthreads();
    for (int o = 1; o < 256; o <<= 1) {
        int t = 0;
        if (threadIdx.x >= o) t = s[threadIdx.x - o];
        __syncthreads();
        s[threadIdx.x] += t;
        __syncthreads();
    }
    if (idx < N_NODES) row_start[idx] = boff[blockIdx.x] + s[threadIdx.x] - v;
}

// ---------- fill CSR: atomic-free (uses precomputed pos) ----------
__global__ void fill_direct(const int* __restrict__ src, const int* __restrict__ dst,
                            const float* __restrict__ ew, const int* __restrict__ pos,
                            const int* __restrict__ row_start, unsigned* __restrict__ csr) {
    int e = blockIdx.x * 256 + threadIdx.x;
    if (e < N_EDGES) {
        int d = dst[e];
        unsigned short hb = __half_as_ushort(__float2half(ew[e]));
        csr[row_start[d] + pos[e]] = ((unsigned)src[e] << 16) | (unsigned)hb;
    }
}

// ---------- deg/dinv from CSR rows (atomic-free segmented sum; 16 lanes/node) ----------
__global__ void deg_dinv_csr(const int* __restrict__ row_start, const unsigned* __restrict__ csr,
                             float* __restrict__ dinv) {
    int t = blockIdx.x * 256 + threadIdx.x;
    int n = t >> 4;
    int l = t & 15;
    if (n >= N_NODES) return;
    int beg = row_start[n], end = row_start[n + 1];
    float s = 0.f;
    for (int i = beg + l; i < end; i += 16) s += ew_of(csr[i]);
    for (int o = 8; o; o >>= 1) s += __shfl_xor(s, o, 16);
    if (l == 0) dinv[n] = rsqrtf(s + 1.0f);
}

// ---------- GEMM1: Yh(f16 pair-major [4][N][32]) = dinv[r]*(X[N,128]@W[128,128]) ----------
__global__ void gemm1_reg(const float* __restrict__ X, const float* __restrict__ W,
                          const float* __restrict__ dinv, __half* __restrict__ Yh, int nrows) {
    __shared__ float Xl[32][132];
    __shared__ float Wl[64][128];
    const int rt = threadIdx.x >> 5;   // 0..7  (4 rows each)
    const int ct = threadIdx.x & 31;   // 0..31 (4 cols each)
    const int base = blockIdx.x * 32;
    for (int i = threadIdx.x; i < 32 * 32; i += 256) {
        int rr = i >> 5, cc = (i & 31) << 2;
        int gr = base + rr;
        float4 v = (gr < nrows) ? *(const float4*)&X[(size_t)gr * 128 + cc]
                                : make_float4(0.f, 0.f, 0.f, 0.f);
        Xl[rr][cc] = v.x; Xl[rr][cc + 1] = v.y; Xl[rr][cc + 2] = v.z; Xl[rr][cc + 3] = v.w;
    }
    float acc[4][4] = {};
    for (int kb = 0; kb < 128; kb += 64) {
        __syncthreads();
        for (int i = threadIdx.x; i < 64 * 32; i += 256) {
            int kk = i >> 5, cc = (i & 31) << 2;
            *(float4*)&Wl[kk][cc] = *(const float4*)&W[(size_t)(kb + kk) * 128 + cc];
        }
        __syncthreads();
        for (int k = 0; k < 64; k += 4) {
            float4 a0 = *(const float4*)&Xl[rt * 4 + 0][kb + k];
            float4 a1 = *(const float4*)&Xl[rt * 4 + 1][kb + k];
            float4 a2 = *(const float4*)&Xl[rt * 4 + 2][kb + k];
            float4 a3 = *(const float4*)&Xl[rt * 4 + 3][kb + k];
            float4 w0 = *(const float4*)&Wl[k + 0][ct * 4];
            float4 w1 = *(const float4*)&Wl[k + 1][ct * 4];
            float4 w2 = *(const float4*)&Wl[k + 2][ct * 4];
            float4 w3 = *(const float4*)&Wl[k + 3][ct * 4];
            #define STEP(av, wv)  \
                acc[0][0] += av##0 * wv.x; acc[0][1] += av##0 * wv.y; acc[0][2] += av##0 * wv.z; acc[0][3] += av##0 * wv.w; \
                acc[1][0] += av##1 * wv.x; acc[1][1] += av##1 * wv.y; acc[1][2] += av##1 * wv.z; acc[1][3] += av##1 * wv.w; \
                acc[2][0] += av##2 * wv.x; acc[2][1] += av##2 * wv.y; acc[2][2] += av##2 * wv.z; acc[2][3] += av##2 * wv.w; \
                acc[3][0] += av##3 * wv.x; acc[3][1] += av##3 * wv.y; acc[3][2] += av##3 * wv.z; acc[3][3] += av##3 * wv.w;
            { float ax0=a0.x, ax1=a1.x, ax2=a2.x, ax3=a3.x; STEP(ax, w0) }
            { float ay0=a0.y, ay1=a1.y, ay2=a2.y, ay3=a3.y; STEP(ay, w1) }
            { float az0=a0.z, az1=a1.z, az2=a2.z, az3=a3.z; STEP(az, w2) }
            { float aw0=a0.w, aw1=a1.w, aw2=a2.w, aw3=a3.w; STEP(aw, w3) }
            #undef STEP
        }
    }
    const int pc = ct >> 3;            // pair-chunk 0..3 (cols j=4ct..4ct+3, pc=j/32)
    const int cw = (ct & 7) * 4;       // offset within pair-chunk
    for (int i = 0; i < 4; ++i) {
        int gr = base + rt * 4 + i;
        if (gr < nrows) {
            float dv = dinv[gr];
            ushort4 u;
            u.x = __half_as_ushort(__float2half(acc[i][0] * dv));
            u.y = __half_as_ushort(__float2half(acc[i][1] * dv));
            u.z = __half_as_ushort(__float2half(acc[i][2] * dv));
            u.w = __half_as_ushort(__float2half(acc[i][3] * dv));
            *(ushort4*)&Yh[((size_t)pc * nrows + gr) * 32 + cw] = u;
        }
    }
}

// ---------- GEMM2: Yh(f16 pair-major [2][N][32]) = dinv[r]*(X[N,128]@W[128,64]) ----------
__global__ void gemm2_reg(const float* __restrict__ X, const float* __restrict__ W,
                          const float* __restrict__ dinv, __half* __restrict__ Yh, int nrows) {
    __shared__ float Xl[32][132];
    __shared__ float Wl[128][64];
    const int rt = threadIdx.x >> 5;   // 0..7  (4 rows)
    const int ct = threadIdx.x & 31;   // 0..31 (2 cols)
    const int base = blockIdx.x * 32;
    for (int i = threadIdx.x; i < 32 * 32; i += 256) {
        int rr = i >> 5, cc = (i & 31) << 2;
        int gr = base + rr;
        float4 v = (gr < nrows) ? *(const float4*)&X[(size_t)gr * 128 + cc]
                                : make_float4(0.f, 0.f, 0.f, 0.f);
        Xl[rr][cc] = v.x; Xl[rr][cc + 1] = v.y; Xl[rr][cc + 2] = v.z; Xl[rr][cc + 3] = v.w;
    }
    for (int i = threadIdx.x; i < 128 * 16; i += 256) {
        int kk = i >> 4, cc = (i & 15) << 2;
        *(float4*)&Wl[kk][cc] = *(const float4*)&W[(size_t)kk * 64 + cc];
    }
    float acc[4][2] = {};
    __syncthreads();
    for (int k = 0; k < 128; k += 4) {
        float4 a0 = *(const float4*)&Xl[rt * 4 + 0][k];
        float4 a1 = *(const float4*)&Xl[rt * 4 + 1][k];
        float4 a2 = *(const float4*)&Xl[rt * 4 + 2][k];
        float4 a3 = *(const float4*)&Xl[rt * 4 + 3][k];
        float2 w0 = *(const float2*)&Wl[k + 0][ct * 2];
        float2 w1 = *(const float2*)&Wl[k + 1][ct * 2];
        float2 w2 = *(const float2*)&Wl[k + 2][ct * 2];
        float2 w3 = *(const float2*)&Wl[k + 3][ct * 2];
        acc[0][0] += a0.x * w0.x; acc[0][1] += a0.x * w0.y;
        acc[1][0] += a1.x * w0.x; acc[1][1] += a1.x * w0.y;
        acc[2][0] += a2.x * w0.x; acc[2][1] += a2.x * w0.y;
        acc[3][0] += a3.x * w0.x; acc[3][1] += a3.x * w0.y;
        acc[0][0] += a0.y * w1.x; acc[0][1] += a0.y * w1.y;
        acc[1][0] += a1.y * w1.x; acc[1][1] += a1.y * w1.y;
        acc[2][0] += a2.y * w1.x; acc[2][1] += a2.y * w1.y;
        acc[3][0] += a3.y * w1.x; acc[3][1] += a3.y * w1.y;
        acc[0][0] += a0.z * w2.x; acc[0][1] += a0.z * w2.y;
        acc[1][0] += a1.z * w2.x; acc[1][1] += a1.z * w2.y;
        acc[2][0] += a2.z * w2.x; acc[2][1] += a2.z * w2.y;
        acc[3][0] += a3.z * w2.x; acc[3][1] += a3.z * w2.y;
        acc[0][0] += a0.w * w3.x; acc[0][1] += a0.w * w3.y;
        acc[1][0] += a1.w * w3.x; acc[1][1] += a1.w * w3.y;
        acc[2][0] += a2.w * w3.x; acc[2][1] += a2.w * w3.y;
        acc[3][0] += a3.w * w3.x; acc[3][1] += a3.w * w3.y;
    }
    const int col0 = ct * 2;
    const int pc   = col0 >> 5;
    const int cw   = col0 & 31;
    for (int i = 0; i < 4; ++i) {
        int gr = base + rt * 4 + i;
        if (gr < nrows) {
            float dv = dinv[gr];
            __half2 hv = __floats2half2_rn(acc[i][0] * dv, acc[i][1] * dv);
            *(__half2*)&Yh[((size_t)pc * nrows + gr) * 32 + cw] = hv;
        }
    }
}

// ---------- CSR aggregation from f16 pair-chunks: 32 lanes/node ----------
// lane kk handles features (2kk,2kk+1) of pair-chunk c; halves split even/odd edges.
// out[n,kg] = relu( dinv[n]*( sum_e ew_e*xws[src_e] + xws[n] ) + b[kg] )
template<int NP>
__global__ void agg_csr_pair(const int* __restrict__ row_start, const unsigned* __restrict__ csr,
                             const __half* __restrict__ xwh, const float* __restrict__ dinv,
                             const float* __restrict__ b, float* __restrict__ out_h) {
    constexpr int OUT = NP * 32;
    const int c    = blockIdx.x % NP;
    const int nb   = blockIdx.x / NP;
    const int n    = nb * 8 + (threadIdx.x >> 5);
    const int kk   = threadIdx.x & 15;
    const int half = (threadIdx.x >> 4) & 1;
    if (n >= N_NODES) return;
    const __half* __restrict__ bp = xwh + ((size_t)c * N_NODES) * 32 + 2 * kk;
    const int beg = row_start[n], end = row_start[n + 1];
    float ax = 0.f, ay = 0.f;
    int i = beg + half;
    for (; i + 6 < end; i += 8) {       // this half: i, i+2, i+4, i+6
        unsigned p0 = csr[i],     p1 = csr[i + 2];
        unsigned p2 = csr[i + 4], p3 = csr[i + 6];
        float2 f0 = __half22float2(*(const __half2*)(bp + (size_t)(p0 >> 16) * 32));
        float2 f1 = __half22float2(*(const __half2*)(bp + (size_t)(p1 >> 16) * 32));
        float2 f2 = __half22float2(*(const __half2*)(bp + (size_t)(p2 >> 16) * 32));
        float2 f3 = __half22float2(*(const __half2*)(bp + (size_t)(p3 >> 16) * 32));
        float e0 = ew_of(p0), e1 = ew_of(p1), e2 = ew_of(p2), e3 = ew_of(p3);
        ax += e0 * f0.x + e1 * f1.x + e2 * f2.x + e3 * f3.x;
        ay += e0 * f0.y + e1 * f1.y + e2 * f2.y + e3 * f3.y;
    }
    for (; i < end; i += 2) {
        unsigned p = csr[i];
        float2 f = __half22float2(*(const __half2*)(bp + (size_t)(p >> 16) * 32));
        float e = ew_of(p);
        ax += e * f.x; ay += e * f.y;
    }
    ax += __shfl_xor(ax, 16);
    ay += __shfl_xor(ay, 16);
    if (half == 0) {
        float2 sf = __half22float2(*(const __half2*)(bp + (size_t)n * 32));
        float dv = dinv[n];
        int kg = c * 32 + 2 * kk;
        float2 o;
        o.x = fmaxf(dv * (ax + sf.x) + b[kg], 0.f);
        o.y = fmaxf(dv * (ay + sf.y) + b[kg + 1], 0.f);
        *(float2*)&out_h[(size_t)n * OUT + kg] = o;
    }
}

// ---------- gate ----------
__global__ void gate_kernel(const float* __restrict__ x1, const float* __restrict__ gW1,
                            const float* __restrict__ gb1, const float* __restrict__ gW2,
                            const float* __restrict__ gb2, const int* __restrict__ batch,
                            float* __restrict__ g, unsigned* __restrict__ gmax_enc) {
    __shared__ float W1l[64 * 32];
    __shared__ float W2l[32];
    __shared__ float b1l[32];
    for (int i = threadIdx.x; i < 64 * 32; i += 256) W1l[i] = gW1[i];
    if (threadIdx.x < 32) { W2l[threadIdx.x] = gW2[threadIdx.x]; b1l[threadIdx.x] = gb1[threadIdx.x]; }
    __syncthreads();
    const float gb2v = gb2[0];
    int n = blockIdx.x * 256 + threadIdx.x;
    bool act = (n < N_NODES);
    float gv = -1e30f;
    int b = 0;
    if (act) {
        const float* row = x1 + (size_t)n * 64;
        float t[32];
        #pragma unroll
        for (int j = 0; j < 32; ++j) t[j] = b1l[j];
        for (int k = 0; k < 64; ++k) {
            float xv = row[k];
            #pragma unroll
            for (int j = 0; j < 32; ++j) t[j] += xv * W1l[k * 32 + j];
        }
        float a = gb2v;
        #pragma unroll
        for (int j = 0; j < 32; ++j) a += fmaxf(t[j], 0.f) * W2l[j];
        gv = a;
        g[n] = a;
        b = batch[n];
    }
    unsigned long long actm = __ballot(act);
    int b0 = __shfl(b, 0);
    bool uniform = (actm == ~0ull) && (__ballot(b == b0) == ~0ull);
    if (uniform) {
        float m = gv;
        for (int o = 32; o; o >>= 1) m = fmaxf(m, __shfl_xor(m, o));
        if ((threadIdx.x & 63) == 0) atomicMax(&gmax_enc[b0], fenc(m));
    } else if (act) {
        atomicMax(&gmax_enc[b], fenc(gv));
    }
}

__global__ void exp_kernel(const float* __restrict__ g, const int* __restrict__ batch,
                           const unsigned* __restrict__ gmax_enc, float* __restrict__ ex,
                           float* __restrict__ den) {
    int n = blockIdx.x * 256 + threadIdx.x;
    bool act = (n < N_NODES);
    float v = 0.f; int b = 0;
    if (act) {
        b = batch[n];
        v = expf(g[n] - fdec(gmax_enc[b]));
        ex[n] = v;
    }
    unsigned long long actm = __ballot(act);
    int b0 = __shfl(b, 0);
    bool uniform = (actm == ~0ull) && (__ballot(b == b0) == ~0ull);
    if (uniform) {
        float s = v;
        for (int o = 32; o; o >>= 1) s += __shfl_xor(s, o);
        if ((threadIdx.x & 63) == 0) atomicAdd(&den[b0], s);
    } else if (act) {
        atomicAdd(&den[b], v);
    }
}

// ---------- pooled[batch] += (ex/den[batch]) * x1 (alpha fused; batch sorted) ----------
__global__ void pool_kernel(const float* __restrict__ x1, const float* __restrict__ ex,
                            const float* __restrict__ den, const int* __restrict__ batch,
                            float* __restrict__ pooled) {
    const int L = 32;
    const int f   = threadIdx.x & 63;
    const int grp = threadIdx.x >> 6;
    int chunk = blockIdx.x * 4 + grp;
    int start = chunk * L;
    if (start >= N_NODES) return;
    int end = min(start + L, N_NODES);
    int cur = batch[start];
    float rden = 1.f / den[cur];
    float acc = 0.f;
    for (int n = start; n < end; ++n) {
        int bb = batch[n];
        if (bb != cur) {
            atomicAdd(&pooled[cur * 64 + f], acc);
            acc = 0.f; cur = bb; rden = 1.f / den[cur];
        }
        acc += ex[n] * rden * x1[(size_t)n * 64 + f];
    }
    atomicAdd(&pooled[cur * 64 + f], acc);
}

__global__ void head_kernel(const float* __restrict__ pooled, const float* __restrict__ fcW1,
                            const float* __restrict__ fcb1, const float* __restrict__ fcW2,
                            const float* __restrict__ fcb2, float* __restrict__ out) {
    __shared__ float P[64 * 64];
    __shared__ float W1l[64 * 128];
    __shared__ float H[64 * 128];
    for (int i = threadIdx.x; i < 64 * 64; i += 256) P[i] = pooled[i];
    for (int i = threadIdx.x; i < 64 * 128; i += 256) W1l[i] = fcW1[i];
    __syncthreads();
    for (int i = threadIdx.x; i < 64 * 128; i += 256) {
        int gi = i >> 7, j = i & 127;
        float a = fcb1[j];
        for (int k = 0; k < 64; ++k) a += P[gi * 64 + k] * W1l[k * 128 + j];
        H[i] = fmaxf(a, 0.f);
    }
    __syncthreads();
    if (threadIdx.x < 64) {
        int gi = threadIdx.x;
        float l0 = fcb2[0], l1 = fcb2[1];
        for (int k = 0; k < 128; ++k) {
            float h = H[gi * 128 + k];
            l0 += h * fcW2[k * 2 + 0];
            l1 += h * fcW2[k * 2 + 1];
        }
        float m = fmaxf(l0, l1);
        float lse = m + logf(expf(l0 - m) + expf(l1 - m));
        out[gi * 2 + 0] = l0 - lse;
        out[gi * 2 + 1] = l1 - lse;
    }
}

extern "C" void kernel_launch(void* const* d_in, const int* in_sizes, int n_in,
                              void* d_out, int out_size, void* d_ws, size_t ws_size,
                              hipStream_t stream) {
    const float* x    = (const float*)d_in[0];
    const int*   ei   = (const int*)d_in[1];
    const float* ew   = (const float*)d_in[2];
    const int*   batch= (const int*)d_in[3];
    const float* W1   = (const float*)d_in[4];
    const float* b1   = (const float*)d_in[5];
    const float* W2   = (const float*)d_in[6];
    const float* b2   = (const float*)d_in[7];
    const float* gW1  = (const float*)d_in[8];
    const float* gb1  = (const float*)d_in[9];
    const float* gW2  = (const float*)d_in[10];
    const float* gb2  = (const float*)d_in[11];
    const float* fcW1 = (const float*)d_in[12];
    const float* fcb1 = (const float*)d_in[13];
    const float* fcW2 = (const float*)d_in[14];
    const float* fcb2 = (const float*)d_in[15];
    float* out = (float*)d_out;

    const int* src = ei;
    const int* dst = ei + N_EDGES;

    const int EB = (N_EDGES + 255) / 256;          // 6250
    const int NB = (N_NODES + 255) / 256;          // 196
    const int NBLK8  = (N_NODES + 7) / 8;          // 6250
    const int NBLK16 = (N_NODES + 15) / 16;        // 3125

    // ---- workspace layout (floats) ----
    float* ws = (float*)d_ws;
    __half* xwh  = (__half*)ws;                    // f16 pair-major [NP][N][32], max 6.4M halves
    float* agg   = ws + 3200000;                   // 6.4M floats (row-major h / x1)
    size_t off = 9600000;
    unsigned* csr   = (unsigned*)(ws + off); off += 1600000;  // packed (src<<16 | f16 ew)
    int*   pos      = (int*)(ws + off);    off += 1600000;
    int*   row_start= (int*)(ws + off);    off += 50176;
    int*   cnt      = (int*)(ws + off);    off += 50176;
    float* dinv     = ws + off;            off += 50176;
    float* g        = ws + off;            off += 50048;
    float* ex       = ws + off;            off += 50048;
    int*   bsum     = (int*)(ws + off);    off += 256;
    int*   boff     = (int*)(ws + off);    off += 256;
    unsigned* gmax  = (unsigned*)(ws + off); off += 64;
    float* den      = ws + off;            off += 64;
    float* pooled   = ws + off;            off += 4096;

    // ---- CSR build (one atomic pass) ----
    hipMemsetAsync(cnt, 0, N_NODES * sizeof(int), stream);
    hist_pos<<<EB, 256, 0, stream>>>(dst, cnt, pos);
    block_sums<<<NB, 256, 0, stream>>>(cnt, bsum);
    scan_bsums<<<1, 256, 0, stream>>>(bsum, boff, NB, row_start + N_NODES);
    scan_counts<<<NB, 256, 0, stream>>>(cnt, boff, row_start);
    fill_direct<<<EB, 256, 0, stream>>>(src, dst, ew, pos, row_start, csr);
    deg_dinv_csr<<<NBLK16, 256, 0, stream>>>(row_start, csr, dinv);

    // ---- conv1: xwh = f16 pair-chunks [4][N][32] ----
    gemm1_reg<<<(N_NODES + 31) / 32, 256, 0, stream>>>(x, W1, dinv, xwh, N_NODES);
    agg_csr_pair<4><<<4 * NBLK8, 256, 0, stream>>>(row_start, csr, xwh, dinv, b1, agg);

    // ---- conv2: xwh = f16 pair-chunks [2][N][32] ----
    gemm2_reg<<<(N_NODES + 31) / 32, 256, 0, stream>>>(agg, W2, dinv, xwh, N_NODES);
    agg_csr_pair<2><<<2 * NBLK8, 256, 0, stream>>>(row_start, csr, xwh, dinv, b2, agg);

    // ---- global attention ----
    hipMemsetAsync(gmax, 0, N_GRAPHS * sizeof(unsigned), stream);
    hipMemsetAsync(den, 0, N_GRAPHS * sizeof(float), stream);
    hipMemsetAsync(pooled, 0, N_GRAPHS * 64 * sizeof(float), stream);
    gate_kernel<<<NB, 256, 0, stream>>>(agg, gW1, gb1, gW2, gb2, batch, g, gmax);
    exp_kernel<<<NB, 256, 0, stream>>>(g, batch, gmax, ex, den);
    int nchunks = (N_NODES + 31) / 32;
    pool_kernel<<<(nchunks + 3) / 4, 256, 0, stream>>>(agg, ex, den, batch, pooled);

    // ---- head ----
    head_kernel<<<1, 256, 0, stream>>>(pooled, fcW1, fcb1, fcW2, fcb2, out);
}

// Round 8
// 338.817 us; speedup vs baseline: 2.7086x; 1.2520x over previous
//
#include <hip/hip_runtime.h>
#include <hip/hip_bf16.h>
#include <hip/hip_fp16.h>

#define N_NODES 50000
#define N_EDGES 1600000
#define N_GRAPHS 64
#define G1BLKS 1563            // ceil(N_NODES/32) gemm1 blocks in mega kernel

// ---------- helpers ----------
__device__ __forceinline__ unsigned fenc(float x) {
    unsigned u = __float_as_uint(x);
    return (u & 0x80000000u) ? ~u : (u | 0x80000000u);
}
__device__ __forceinline__ float fdec(unsigned e) {
    return (e & 0x80000000u) ? __uint_as_float(e & 0x7fffffffu) : __uint_as_float(~e);
}
__device__ __forceinline__ float ew_of(unsigned p) {
    return __half2float(__ushort_as_half((unsigned short)(p & 0xFFFFu)));
}

// ---------- MEGA: blocks [0,G1BLKS) = gemm1 (unscaled, W from global); rest = hist_pos ----------
__global__ void mega1(const float* __restrict__ X, const float* __restrict__ W,
                      __half* __restrict__ Yh, const int* __restrict__ dst,
                      int* __restrict__ cnt, int* __restrict__ pos) {
    __shared__ float Xl[32][132];
    if (blockIdx.x >= G1BLKS) {
        int e = (blockIdx.x - G1BLKS) * 256 + threadIdx.x;
        if (e < N_EDGES) pos[e] = atomicAdd(&cnt[dst[e]], 1);
        return;
    }
    // ---- gemm1: Yh(f16 pair-major [4][N][32]) = X[N,128] @ W[128,128] (unscaled) ----
    const int rt = threadIdx.x >> 5;   // 0..7  (4 rows each)
    const int ct = threadIdx.x & 31;   // 0..31 (4 cols each)
    const int base = blockIdx.x * 32;
    for (int i = threadIdx.x; i < 32 * 32; i += 256) {
        int rr = i >> 5, cc = (i & 31) << 2;
        int gr = base + rr;
        float4 v = (gr < N_NODES) ? *(const float4*)&X[(size_t)gr * 128 + cc]
                                  : make_float4(0.f, 0.f, 0.f, 0.f);
        Xl[rr][cc] = v.x; Xl[rr][cc + 1] = v.y; Xl[rr][cc + 2] = v.z; Xl[rr][cc + 3] = v.w;
    }
    __syncthreads();
    float acc[4][4] = {};
    for (int k = 0; k < 128; k += 4) {
        float4 a0 = *(const float4*)&Xl[rt * 4 + 0][k];
        float4 a1 = *(const float4*)&Xl[rt * 4 + 1][k];
        float4 a2 = *(const float4*)&Xl[rt * 4 + 2][k];
        float4 a3 = *(const float4*)&Xl[rt * 4 + 3][k];
        float4 w0 = *(const float4*)&W[(size_t)(k + 0) * 128 + ct * 4];
        float4 w1 = *(const float4*)&W[(size_t)(k + 1) * 128 + ct * 4];
        float4 w2 = *(const float4*)&W[(size_t)(k + 2) * 128 + ct * 4];
        float4 w3 = *(const float4*)&W[(size_t)(k + 3) * 128 + ct * 4];
        #define STEP(av, wv)  \
            acc[0][0] += av##0 * wv.x; acc[0][1] += av##0 * wv.y; acc[0][2] += av##0 * wv.z; acc[0][3] += av##0 * wv.w; \
            acc[1][0] += av##1 * wv.x; acc[1][1] += av##1 * wv.y; acc[1][2] += av##1 * wv.z; acc[1][3] += av##1 * wv.w; \
            acc[2][0] += av##2 * wv.x; acc[2][1] += av##2 * wv.y; acc[2][2] += av##2 * wv.z; acc[2][3] += av##2 * wv.w; \
            acc[3][0] += av##3 * wv.x; acc[3][1] += av##3 * wv.y; acc[3][2] += av##3 * wv.z; acc[3][3] += av##3 * wv.w;
        { float ax0=a0.x, ax1=a1.x, ax2=a2.x, ax3=a3.x; STEP(ax, w0) }
        { float ay0=a0.y, ay1=a1.y, ay2=a2.y, ay3=a3.y; STEP(ay, w1) }
        { float az0=a0.z, az1=a1.z, az2=a2.z, az3=a3.z; STEP(az, w2) }
        { float aw0=a0.w, aw1=a1.w, aw2=a2.w, aw3=a3.w; STEP(aw, w3) }
        #undef STEP
    }
    const int pc = ct >> 3;            // pair-chunk 0..3
    const int cw = (ct & 7) * 4;       // offset within pair-chunk row
    for (int i = 0; i < 4; ++i) {
        int gr = base + rt * 4 + i;
        if (gr < N_NODES) {
            ushort4 u;
            u.x = __half_as_ushort(__float2half(acc[i][0]));
            u.y = __half_as_ushort(__float2half(acc[i][1]));
            u.z = __half_as_ushort(__float2half(acc[i][2]));
            u.w = __half_as_ushort(__float2half(acc[i][3]));
            *(ushort4*)&Yh[((size_t)pc * N_NODES + gr) * 32 + cw] = u;
        }
    }
}

// ---------- prefix-scan (hierarchical, 3 kernels) ----------
__global__ void block_sums(const int* __restrict__ cnt, int* __restrict__ bsum) {
    __shared__ int s[256];
    int idx = blockIdx.x * 256 + threadIdx.x;
    s[threadIdx.x] = (idx < N_NODES) ? cnt[idx] : 0;
    __syncthreads();
    for (int o = 128; o; o >>= 1) {
        if (threadIdx.x < o) s[threadIdx.x] += s[threadIdx.x + o];
        __syncthreads();
    }
    if (threadIdx.x == 0) bsum[blockIdx.x] = s[0];
}

__global__ void scan_bsums(const int* __restrict__ bsum, int* __restrict__ boff,
                           int nb, int* __restrict__ row_start_last) {
    __shared__ int s[256];
    int v = (threadIdx.x < nb) ? bsum[threadIdx.x] : 0;
    s[threadIdx.x] = v;
    __syncthreads();
    for (int o = 1; o < 256; o <<= 1) {
        int t = 0;
        if (threadIdx.x >= o) t = s[threadIdx.x - o];
        __syncthreads();
        s[threadIdx.x] += t;
        __syncthreads();
    }
    if (threadIdx.x < nb) boff[threadIdx.x] = s[threadIdx.x] - v;   // exclusive
    if (threadIdx.x == 0) *row_start_last = N_EDGES;
}

__global__ void scan_counts(const int* __restrict__ cnt, const int* __restrict__ boff,
                            int* __restrict__ row_start) {
    __shared__ int s[256];
    int idx = blockIdx.x * 256 + threadIdx.x;
    int v = (idx < N_NODES) ? cnt[idx] : 0;
    s[threadIdx.x] = v;
    __syncthreads();
    for (int o = 1; o < 256; o <<= 1) {
        int t = 0;
        if (threadIdx.x >= o) t = s[threadIdx.x - o];
        __syncthreads();
        s[threadIdx.x] += t;
        __syncthreads();
    }
    if (idx < N_NODES) row_start[idx] = boff[blockIdx.x] + s[threadIdx.x] - v;
}

// ---------- fill CSR: atomic-free (uses precomputed pos) ----------
__global__ void fill_direct(const int* __restrict__ src, const int* __restrict__ dst,
                            const float* __restrict__ ew, const int* __restrict__ pos,
                            const int* __restrict__ row_start, unsigned* __restrict__ csr) {
    int e = blockIdx.x * 256 + threadIdx.x;
    if (e < N_EDGES) {
        int d = dst[e];
        unsigned short hb = __half_as_ushort(__float2half(ew[e]));
        csr[row_start[d] + pos[e]] = ((unsigned)src[e] << 16) | (unsigned)hb;
    }
}

// ---------- deg/dinv from CSR rows (atomic-free segmented sum; 16 lanes/node) ----------
__global__ void deg_dinv_csr(const int* __restrict__ row_start, const unsigned* __restrict__ csr,
                             float* __restrict__ dinv) {
    int t = blockIdx.x * 256 + threadIdx.x;
    int n = t >> 4;
    int l = t & 15;
    if (n >= N_NODES) return;
    int beg = row_start[n], end = row_start[n + 1];
    float s = 0.f;
    for (int i = beg + l; i < end; i += 16) s += ew_of(csr[i]);
    for (int o = 8; o; o >>= 1) s += __shfl_xor(s, o, 16);
    if (l == 0) dinv[n] = rsqrtf(s + 1.0f);
}

// ---------- scale xwh[4][N][32] rows by dinv[n] (8 halves per thread) ----------
__global__ void scale_xwh(__half* __restrict__ xwh, const float* __restrict__ dinv) {
    const size_t tot = (size_t)4 * N_NODES * 32 / 8;
    size_t i = (size_t)blockIdx.x * 256 + threadIdx.x;
    if (i >= tot) return;
    size_t h0 = i * 8;
    int n = (int)((h0 >> 5) % N_NODES);
    float dv = dinv[n];
    __half2* p = (__half2*)(xwh + h0);
    #pragma unroll
    for (int j = 0; j < 4; ++j) {
        float2 f = __half22float2(p[j]);
        p[j] = __floats2half2_rn(f.x * dv, f.y * dv);
    }
}

// ---------- GEMM2: Yh(f16 pair-major [2][N][32]) = dinv[r]*(X[N,128]@W[128,64]) ----------
__global__ void gemm2_reg(const float* __restrict__ X, const float* __restrict__ W,
                          const float* __restrict__ dinv, __half* __restrict__ Yh, int nrows) {
    __shared__ float Xl[32][132];
    __shared__ float Wl[128][64];
    const int rt = threadIdx.x >> 5;   // 0..7  (4 rows)
    const int ct = threadIdx.x & 31;   // 0..31 (2 cols)
    const int base = blockIdx.x * 32;
    for (int i = threadIdx.x; i < 32 * 32; i += 256) {
        int rr = i >> 5, cc = (i & 31) << 2;
        int gr = base + rr;
        float4 v = (gr < nrows) ? *(const float4*)&X[(size_t)gr * 128 + cc]
                                : make_float4(0.f, 0.f, 0.f, 0.f);
        Xl[rr][cc] = v.x; Xl[rr][cc + 1] = v.y; Xl[rr][cc + 2] = v.z; Xl[rr][cc + 3] = v.w;
    }
    for (int i = threadIdx.x; i < 128 * 16; i += 256) {
        int kk = i >> 4, cc = (i & 15) << 2;
        *(float4*)&Wl[kk][cc] = *(const float4*)&W[(size_t)kk * 64 + cc];
    }
    float acc[4][2] = {};
    __syncthreads();
    for (int k = 0; k < 128; k += 4) {
        float4 a0 = *(const float4*)&Xl[rt * 4 + 0][k];
        float4 a1 = *(const float4*)&Xl[rt * 4 + 1][k];
        float4 a2 = *(const float4*)&Xl[rt * 4 + 2][k];
        float4 a3 = *(const float4*)&Xl[rt * 4 + 3][k];
        float2 w0 = *(const float2*)&Wl[k + 0][ct * 2];
        float2 w1 = *(const float2*)&Wl[k + 1][ct * 2];
        float2 w2 = *(const float2*)&Wl[k + 2][ct * 2];
        float2 w3 = *(const float2*)&Wl[k + 3][ct * 2];
        acc[0][0] += a0.x * w0.x; acc[0][1] += a0.x * w0.y;
        acc[1][0] += a1.x * w0.x; acc[1][1] += a1.x * w0.y;
        acc[2][0] += a2.x * w0.x; acc[2][1] += a2.x * w0.y;
        acc[3][0] += a3.x * w0.x; acc[3][1] += a3.x * w0.y;
        acc[0][0] += a0.y * w1.x; acc[0][1] += a0.y * w1.y;
        acc[1][0] += a1.y * w1.x; acc[1][1] += a1.y * w1.y;
        acc[2][0] += a2.y * w1.x; acc[2][1] += a2.y * w1.y;
        acc[3][0] += a3.y * w1.x; acc[3][1] += a3.y * w1.y;
        acc[0][0] += a0.z * w2.x; acc[0][1] += a0.z * w2.y;
        acc[1][0] += a1.z * w2.x; acc[1][1] += a1.z * w2.y;
        acc[2][0] += a2.z * w2.x; acc[2][1] += a2.z * w2.y;
        acc[3][0] += a3.z * w2.x; acc[3][1] += a3.z * w2.y;
        acc[0][0] += a0.w * w3.x; acc[0][1] += a0.w * w3.y;
        acc[1][0] += a1.w * w3.x; acc[1][1] += a1.w * w3.y;
        acc[2][0] += a2.w * w3.x; acc[2][1] += a2.w * w3.y;
        acc[3][0] += a3.w * w3.x; acc[3][1] += a3.w * w3.y;
    }
    const int col0 = ct * 2;
    const int pc   = col0 >> 5;
    const int cw   = col0 & 31;
    for (int i = 0; i < 4; ++i) {
        int gr = base + rt * 4 + i;
        if (gr < nrows) {
            float dv = dinv[gr];
            __half2 hv = __floats2half2_rn(acc[i][0] * dv, acc[i][1] * dv);
            *(__half2*)&Yh[((size_t)pc * nrows + gr) * 32 + cw] = hv;
        }
    }
}

// ---------- CSR aggregation from f16 pair-chunks: 32 lanes/node ----------
template<int NP>
__global__ void agg_csr_pair(const int* __restrict__ row_start, const unsigned* __restrict__ csr,
                             const __half* __restrict__ xwh, const float* __restrict__ dinv,
                             const float* __restrict__ b, float* __restrict__ out_h) {
    constexpr int OUT = NP * 32;
    const int c    = blockIdx.x % NP;
    const int nb   = blockIdx.x / NP;
    const int n    = nb * 8 + (threadIdx.x >> 5);
    const int kk   = threadIdx.x & 15;
    const int half = (threadIdx.x >> 4) & 1;
    if (n >= N_NODES) return;
    const __half* __restrict__ bp = xwh + ((size_t)c * N_NODES) * 32 + 2 * kk;
    const int beg = row_start[n], end = row_start[n + 1];
    float ax = 0.f, ay = 0.f;
    int i = beg + half;
    for (; i + 6 < end; i += 8) {
        unsigned p0 = csr[i],     p1 = csr[i + 2];
        unsigned p2 = csr[i + 4], p3 = csr[i + 6];
        float2 f0 = __half22float2(*(const __half2*)(bp + (size_t)(p0 >> 16) * 32));
        float2 f1 = __half22float2(*(const __half2*)(bp + (size_t)(p1 >> 16) * 32));
        float2 f2 = __half22float2(*(const __half2*)(bp + (size_t)(p2 >> 16) * 32));
        float2 f3 = __half22float2(*(const __half2*)(bp + (size_t)(p3 >> 16) * 32));
        float e0 = ew_of(p0), e1 = ew_of(p1), e2 = ew_of(p2), e3 = ew_of(p3);
        ax += e0 * f0.x + e1 * f1.x + e2 * f2.x + e3 * f3.x;
        ay += e0 * f0.y + e1 * f1.y + e2 * f2.y + e3 * f3.y;
    }
    for (; i < end; i += 2) {
        unsigned p = csr[i];
        float2 f = __half22float2(*(const __half2*)(bp + (size_t)(p >> 16) * 32));
        float e = ew_of(p);
        ax += e * f.x; ay += e * f.y;
    }
    ax += __shfl_xor(ax, 16);
    ay += __shfl_xor(ay, 16);
    if (half == 0) {
        float2 sf = __half22float2(*(const __half2*)(bp + (size_t)n * 32));
        float dv = dinv[n];
        int kg = c * 32 + 2 * kk;
        float2 o;
        o.x = fmaxf(dv * (ax + sf.x) + b[kg], 0.f);
        o.y = fmaxf(dv * (ay + sf.y) + b[kg + 1], 0.f);
        *(float2*)&out_h[(size_t)n * OUT + kg] = o;
    }
}

// ---------- gate ----------
__global__ void gate_kernel(const float* __restrict__ x1, const float* __restrict__ gW1,
                            const float* __restrict__ gb1, const float* __restrict__ gW2,
                            const float* __restrict__ gb2, const int* __restrict__ batch,
                            float* __restrict__ g, unsigned* __restrict__ gmax_enc) {
    __shared__ float W1l[64 * 32];
    __shared__ float W2l[32];
    __shared__ float b1l[32];
    for (int i = threadIdx.x; i < 64 * 32; i += 256) W1l[i] = gW1[i];
    if (threadIdx.x < 32) { W2l[threadIdx.x] = gW2[threadIdx.x]; b1l[threadIdx.x] = gb1[threadIdx.x]; }
    __syncthreads();
    const float gb2v = gb2[0];
    int n = blockIdx.x * 256 + threadIdx.x;
    bool act = (n < N_NODES);
    float gv = -1e30f;
    int b = 0;
    if (act) {
        const float* row = x1 + (size_t)n * 64;
        float t[32];
        #pragma unroll
        for (int j = 0; j < 32; ++j) t[j] = b1l[j];
        for (int k = 0; k < 64; ++k) {
            float xv = row[k];
            #pragma unroll
            for (int j = 0; j < 32; ++j) t[j] += xv * W1l[k * 32 + j];
        }
        float a = gb2v;
        #pragma unroll
        for (int j = 0; j < 32; ++j) a += fmaxf(t[j], 0.f) * W2l[j];
        gv = a;
        g[n] = a;
        b = batch[n];
    }
    unsigned long long actm = __ballot(act);
    int b0 = __shfl(b, 0);
    bool uniform = (actm == ~0ull) && (__ballot(b == b0) == ~0ull);
    if (uniform) {
        float m = gv;
        for (int o = 32; o; o >>= 1) m = fmaxf(m, __shfl_xor(m, o));
        if ((threadIdx.x & 63) == 0) atomicMax(&gmax_enc[b0], fenc(m));
    } else if (act) {
        atomicMax(&gmax_enc[b], fenc(gv));
    }
}

__global__ void exp_kernel(const float* __restrict__ g, const int* __restrict__ batch,
                           const unsigned* __restrict__ gmax_enc, float* __restrict__ ex,
                           float* __restrict__ den) {
    int n = blockIdx.x * 256 + threadIdx.x;
    bool act = (n < N_NODES);
    float v = 0.f; int b = 0;
    if (act) {
        b = batch[n];
        v = expf(g[n] - fdec(gmax_enc[b]));
        ex[n] = v;
    }
    unsigned long long actm = __ballot(act);
    int b0 = __shfl(b, 0);
    bool uniform = (actm == ~0ull) && (__ballot(b == b0) == ~0ull);
    if (uniform) {
        float s = v;
        for (int o = 32; o; o >>= 1) s += __shfl_xor(s, o);
        if ((threadIdx.x & 63) == 0) atomicAdd(&den[b0], s);
    } else if (act) {
        atomicAdd(&den[b], v);
    }
}

// ---------- pooled[batch] += (ex/den[batch]) * x1 ----------
__global__ void pool_kernel(const float* __restrict__ x1, const float* __restrict__ ex,
                            const float* __restrict__ den, const int* __restrict__ batch,
                            float* __restrict__ pooled) {
    const int L = 32;
    const int f   = threadIdx.x & 63;
    const int grp = threadIdx.x >> 6;
    int chunk = blockIdx.x * 4 + grp;
    int start = chunk * L;
    if (start >= N_NODES) return;
    int end = min(start + L, N_NODES);
    int cur = batch[start];
    float rden = 1.f / den[cur];
    float acc = 0.f;
    for (int n = start; n < end; ++n) {
        int bb = batch[n];
        if (bb != cur) {
            atomicAdd(&pooled[cur * 64 + f], acc);
            acc = 0.f; cur = bb; rden = 1.f / den[cur];
        }
        acc += ex[n] * rden * x1[(size_t)n * 64 + f];
    }
    atomicAdd(&pooled[cur * 64 + f], acc);
}

// ---------- head: one block per graph ----------
__global__ void head_kernel(const float* __restrict__ pooled, const float* __restrict__ fcW1,
                            const float* __restrict__ fcb1, const float* __restrict__ fcW2,
                            const float* __restrict__ fcb2, float* __restrict__ out) {
    __shared__ float P[64];
    __shared__ float r0[2], r1[2];
    const int gi = blockIdx.x;
    if (threadIdx.x < 64) P[threadIdx.x] = pooled[gi * 64 + threadIdx.x];
    __syncthreads();
    const int j = threadIdx.x;                     // 0..127
    float a = fcb1[j];
    #pragma unroll 8
    for (int k = 0; k < 64; ++k) a += P[k] * fcW1[k * 128 + j];
    float h = fmaxf(a, 0.f);
    float p0 = h * fcW2[j * 2 + 0];
    float p1 = h * fcW2[j * 2 + 1];
    for (int o = 32; o; o >>= 1) { p0 += __shfl_xor(p0, o); p1 += __shfl_xor(p1, o); }
    if ((threadIdx.x & 63) == 0) { r0[threadIdx.x >> 6] = p0; r1[threadIdx.x >> 6] = p1; }
    __syncthreads();
    if (threadIdx.x == 0) {
        float l0 = r0[0] + r0[1] + fcb2[0];
        float l1 = r1[0] + r1[1] + fcb2[1];
        float m = fmaxf(l0, l1);
        float lse = m + logf(expf(l0 - m) + expf(l1 - m));
        out[gi * 2 + 0] = l0 - lse;
        out[gi * 2 + 1] = l1 - lse;
    }
}

extern "C" void kernel_launch(void* const* d_in, const int* in_sizes, int n_in,
                              void* d_out, int out_size, void* d_ws, size_t ws_size,
                              hipStream_t stream) {
    const float* x    = (const float*)d_in[0];
    const int*   ei   = (const int*)d_in[1];
    const float* ew   = (const float*)d_in[2];
    const int*   batch= (const int*)d_in[3];
    const float* W1   = (const float*)d_in[4];
    const float* b1   = (const float*)d_in[5];
    const float* W2   = (const float*)d_in[6];
    const float* b2   = (const float*)d_in[7];
    const float* gW1  = (const float*)d_in[8];
    const float* gb1  = (const float*)d_in[9];
    const float* gW2  = (const float*)d_in[10];
    const float* gb2  = (const float*)d_in[11];
    const float* fcW1 = (const float*)d_in[12];
    const float* fcb1 = (const float*)d_in[13];
    const float* fcW2 = (const float*)d_in[14];
    const float* fcb2 = (const float*)d_in[15];
    float* out = (float*)d_out;

    const int* src = ei;
    const int* dst = ei + N_EDGES;

    const int EB = (N_EDGES + 255) / 256;          // 6250
    const int NB = (N_NODES + 255) / 256;          // 196
    const int NBLK8  = (N_NODES + 7) / 8;          // 6250
    const int NBLK16 = (N_NODES + 15) / 16;        // 3125

    // ---- workspace layout (floats) ----
    float* ws = (float*)d_ws;
    __half* xwh  = (__half*)ws;                    // f16 pair-major [NP][N][32], max 6.4M halves
    float* agg   = ws + 3200000;                   // 6.4M floats (row-major h / x1)
    size_t off = 9600000;
    unsigned* csr   = (unsigned*)(ws + off); off += 1600000;  // packed (src<<16 | f16 ew)
    int*   pos      = (int*)(ws + off);    off += 1600000;
    int*   row_start= (int*)(ws + off);    off += 50176;
    int*   cnt      = (int*)(ws + off);    off += 50176;
    float* dinv     = ws + off;            off += 50176;
    float* g        = ws + off;            off += 50048;
    float* ex       = ws + off;            off += 50048;
    int*   bsum     = (int*)(ws + off);    off += 256;
    int*   boff     = (int*)(ws + off);    off += 256;
    unsigned* gmax  = (unsigned*)(ws + off); off += 64;
    float* den      = ws + off;            off += 64;
    float* pooled   = ws + off;            off += 4096;

    // ---- phase 1: gemm1 (unscaled) co-dispatched with hist_pos ----
    hipMemsetAsync(cnt, 0, N_NODES * sizeof(int), stream);
    mega1<<<G1BLKS + EB, 256, 0, stream>>>(x, W1, xwh, dst, cnt, pos);

    // ---- CSR finish ----
    block_sums<<<NB, 256, 0, stream>>>(cnt, bsum);
    scan_bsums<<<1, 256, 0, stream>>>(bsum, boff, NB, row_start + N_NODES);
    scan_counts<<<NB, 256, 0, stream>>>(cnt, boff, row_start);
    fill_direct<<<EB, 256, 0, stream>>>(src, dst, ew, pos, row_start, csr);
    deg_dinv_csr<<<NBLK16, 256, 0, stream>>>(row_start, csr, dinv);
    scale_xwh<<<(4 * N_NODES * 32 / 8 + 255) / 256, 256, 0, stream>>>(xwh, dinv);

    // ---- conv1 agg ----
    agg_csr_pair<4><<<4 * NBLK8, 256, 0, stream>>>(row_start, csr, xwh, dinv, b1, agg);

    // ---- conv2 ----
    gemm2_reg<<<(N_NODES + 31) / 32, 256, 0, stream>>>(agg, W2, dinv, xwh, N_NODES);
    agg_csr_pair<2><<<2 * NBLK8, 256, 0, stream>>>(row_start, csr, xwh, dinv, b2, agg);

    // ---- global attention ----
    hipMemsetAsync(gmax, 0, N_GRAPHS * sizeof(unsigned), stream);
    hipMemsetAsync(den, 0, N_GRAPHS * sizeof(float), stream);
    hipMemsetAsync(pooled, 0, N_GRAPHS * 64 * sizeof(float), stream);
    gate_kernel<<<NB, 256, 0, stream>>>(agg, gW1, gb1, gW2, gb2, batch, g, gmax);
    exp_kernel<<<NB, 256, 0, stream>>>(g, batch, gmax, ex, den);
    int nchunks = (N_NODES + 31) / 32;
    pool_kernel<<<(nchunks + 3) / 4, 256, 0, stream>>>(agg, ex, den, batch, pooled);

    // ---- head (64 blocks) ----
    head_kernel<<<N_GRAPHS, 128, 0, stream>>>(pooled, fcW1, fcb1, fcW2, fcb2, out);
}